// Round 8
// baseline (666.395 us; speedup 1.0000x reference)
//
#include <hip/hip_runtime.h>

using u16 = unsigned short;
using u32 = unsigned int;

#define M_NODES 50000
#define E_EDGES 600000
#define EPS_BN 1e-5f
#define BKT 48

typedef __attribute__((ext_vector_type(8))) short bf16x8;
typedef __attribute__((ext_vector_type(4))) float f32x4;

__device__ __forceinline__ float bf2f(u16 v) {
  union { u32 u; float f; } x; x.u = ((u32)v) << 16; return x.f;
}
__device__ __forceinline__ float lo16f(u32 v) {
  union { u32 u; float f; } x; x.u = v << 16; return x.f;
}
__device__ __forceinline__ float hi16f(u32 v) {
  union { u32 u; float f; } x; x.u = v & 0xffff0000u; return x.f;
}
__device__ __forceinline__ u16 f2bf(float f) {
  union { float f; u32 u; } x; x.f = f;
  u32 r = x.u + 0x7fffu + ((x.u >> 16) & 1u);
  return (u16)(r >> 16);
}

#define GLOAD_LDS16(g, l)                                                        \
  __builtin_amdgcn_global_load_lds((const __attribute__((address_space(1))) void*)(g), \
                                   (__attribute__((address_space(3))) void*)(l), 16, 0, 0)

// ---------------- bucket build ----------------
__global__ void k_place(const int* __restrict__ src, const int* __restrict__ dst,
                        int* __restrict__ cnt, int* __restrict__ bucket, int n) {
  int e = blockIdx.x * blockDim.x + threadIdx.x;
  if (e < n) {
    int d = dst[e];
    int p = atomicAdd(&cnt[d], 1);
    if (p < BKT) bucket[d * BKT + p] = src[e];
  }
}

// ---------------- weight prep: fp32 -> bf16 packed ----------------
// [0,32768) encW2 [128][256]; [32768+i*32768) conv i: [128][256] = [Wl|Wr];
// [196608,229376) decW1 [256][128]
__global__ __launch_bounds__(256) void k_prep(const float* __restrict__ encW2,
                                              const float* __restrict__ Wl,
                                              const float* __restrict__ Wr,
                                              const float* __restrict__ decW1,
                                              u16* __restrict__ Bp) {
  int e = blockIdx.x * 256 + threadIdx.x;
  float v;
  if (e < 32768) {
    v = encW2[e];
  } else if (e < 196608) {
    int r = e - 32768;
    int i = r >> 15;
    int rr = r & 32767;
    int n = rr >> 8;
    int k = rr & 255;
    v = (k < 128) ? Wl[i * 16384 + n * 128 + k] : Wr[i * 16384 + n * 128 + (k - 128)];
  } else {
    v = decW1[e - 196608];
  }
  Bp[e] = f2bf(v);
}

// ================= fused conv: gather(+BN+relu) -> LDS A-tile -> MFMA GEMM =================
// Block: 64 nodes x 128 out-cols, K=256 ([mean|root]). 4 waves.
template <int TRANS, int DO_STATS>
__global__ __launch_bounds__(256) void k_conv(
    const u16* __restrict__ z, const int* __restrict__ cnt,
    const int* __restrict__ bucket,
    const float* __restrict__ ssum_in, const float* __restrict__ gamma,
    const float* __restrict__ beta,
    const u16* __restrict__ Bp, const float* __restrict__ bias,
    u16* __restrict__ C, int M, float* __restrict__ ssum_out) {
  __shared__ __align__(16) u16 As[8][2048];   // 8 K-panels x (64 rows x 32)
  __shared__ __align__(16) u16 Bs[2][4096];   // dbuf: 128 rows x 32
  __shared__ float s_sc[256];
  __shared__ float bnbuf[256];
  int t = threadIdx.x;
  int lane = t & 63;
  int w = t >> 6;
  int m0 = blockIdx.x * 64;

  auto stageB = [&](int kt, int b) {
    #pragma unroll
    for (int j = 0; j < 2; ++j) {
      int s = (w * 2 + j) * 64 + lane;
      int row = s >> 2;
      int cc = (s & 3) ^ ((row >> 1) & 3);
      const u16* src = Bp + (size_t)row * 256 + kt * 32 + cc * 8;
      GLOAD_LDS16(src, &Bs[b][(w * 2 + j) * 512]);
    }
  };

  stageB(0, 0);
  if (DO_STATS) bnbuf[t] = 0.f;
  if (TRANS) {
    if (t < 128) {
      float m = ssum_in[t] * (1.0f / M_NODES);
      float var = ssum_in[128 + t] * (1.0f / M_NODES) - m * m;
      float s = gamma[t] * rsqrtf(var + EPS_BN);
      s_sc[t] = s;
      s_sc[128 + t] = beta[t] - m * s;
    }
    __syncthreads();
  }

  int slot = lane >> 4;
  int fc = lane & 15;
  float sreg[8], treg[8];
  if (TRANS) {
    #pragma unroll
    for (int i = 0; i < 8; ++i) {
      sreg[i] = s_sc[fc * 8 + i];
      treg[i] = s_sc[128 + fc * 8 + i];
    }
  }

  // ---- gather phase: wave w builds rows w*16..w*16+15 of the A-tile ----
  for (int r = 0; r < 16; ++r) {
    int nl = w * 16 + r;
    int ng = m0 + nl;
    float a[8] = {};
    int deg = 0;
    if (ng < M) {
      deg = cnt[ng];
      int nd = deg < BKT ? deg : BKT;
      const int* bk = bucket + (size_t)ng * BKT;
      for (int j = slot; j < nd; j += 4) {
        int sI = bk[j];
        uint4 v = *(const uint4*)(z + (size_t)sI * 128 + fc * 8);
        float f[8] = {lo16f(v.x), hi16f(v.x), lo16f(v.y), hi16f(v.y),
                      lo16f(v.z), hi16f(v.z), lo16f(v.w), hi16f(v.w)};
        #pragma unroll
        for (int i = 0; i < 8; ++i) {
          float vv = TRANS ? fmaxf(fmaf(f[i], sreg[i], treg[i]), 0.f) : f[i];
          a[i] += vv;
        }
      }
    }
    #pragma unroll
    for (int i = 0; i < 8; ++i) {
      a[i] += __shfl_xor(a[i], 16, 64);
      a[i] += __shfl_xor(a[i], 32, 64);
    }
    int swz = nl * 32 + ((fc & 3) ^ ((nl >> 1) & 3)) * 8;
    if (slot == 0) {  // mean -> panels 0..3
      float inv = 1.0f / (float)(deg > 1 ? deg : 1);
      uint4 rr;
      rr.x = (u32)f2bf(a[0] * inv) | ((u32)f2bf(a[1] * inv) << 16);
      rr.y = (u32)f2bf(a[2] * inv) | ((u32)f2bf(a[3] * inv) << 16);
      rr.z = (u32)f2bf(a[4] * inv) | ((u32)f2bf(a[5] * inv) << 16);
      rr.w = (u32)f2bf(a[6] * inv) | ((u32)f2bf(a[7] * inv) << 16);
      *(uint4*)&As[fc >> 2][swz] = rr;
    }
    if (slot == 1) {  // root (BN'd) -> panels 4..7
      uint4 rr = {0, 0, 0, 0};
      if (ng < M) {
        uint4 v = *(const uint4*)(z + (size_t)ng * 128 + fc * 8);
        float f[8] = {lo16f(v.x), hi16f(v.x), lo16f(v.y), hi16f(v.y),
                      lo16f(v.z), hi16f(v.z), lo16f(v.w), hi16f(v.w)};
        u16 o[8];
        #pragma unroll
        for (int i = 0; i < 8; ++i) {
          float vv = TRANS ? fmaxf(fmaf(f[i], sreg[i], treg[i]), 0.f) : f[i];
          o[i] = f2bf(vv);
        }
        rr.x = (u32)o[0] | ((u32)o[1] << 16);
        rr.y = (u32)o[2] | ((u32)o[3] << 16);
        rr.z = (u32)o[4] | ((u32)o[5] << 16);
        rr.w = (u32)o[6] | ((u32)o[7] << 16);
      }
      *(uint4*)&As[4 + (fc >> 2)][swz] = rr;
    }
  }
  __syncthreads();  // A-tile complete, Bs0 landed

  // ---- K-loop (single-barrier dbuf, A already in LDS) ----
  f32x4 acc[2][4] = {};
  int c16 = lane >> 4;
  #pragma unroll
  for (int kt = 0; kt < 8; ++kt) {
    const int b = kt & 1;
    if (kt + 1 < 8) stageB(kt + 1, (kt + 1) & 1);
    bf16x8 af[2], bfr[4];
    #pragma unroll
    for (int mf = 0; mf < 2; ++mf) {
      int row = (w & 1) * 32 + mf * 16 + (lane & 15);
      int cs = c16 ^ ((row >> 1) & 3);
      af[mf] = *(const bf16x8*)&As[kt][row * 32 + cs * 8];
    }
    #pragma unroll
    for (int nf = 0; nf < 4; ++nf) {
      int row = (w >> 1) * 64 + nf * 16 + (lane & 15);
      int cs = c16 ^ ((row >> 1) & 3);
      bfr[nf] = *(const bf16x8*)&Bs[b][row * 32 + cs * 8];
    }
    #pragma unroll
    for (int mf = 0; mf < 2; ++mf)
      #pragma unroll
      for (int nf = 0; nf < 4; ++nf)
        acc[mf][nf] = __builtin_amdgcn_mfma_f32_16x16x32_bf16(af[mf], bfr[nf], acc[mf][nf], 0, 0, 0);
    __syncthreads();
  }

  // ---- epilogue ----
  float breg[4];
  #pragma unroll
  for (int nf = 0; nf < 4; ++nf)
    breg[nf] = bias[(w >> 1) * 64 + nf * 16 + (lane & 15)];

  float cs_[4] = {}, cq_[4] = {};
  #pragma unroll
  for (int mf = 0; mf < 2; ++mf) {
    #pragma unroll
    for (int j = 0; j < 4; ++j) {
      int rl = (w & 1) * 32 + mf * 16 + c16 * 4 + j;
      int rg = m0 + rl;
      if (rg < M) {
        #pragma unroll
        for (int nf = 0; nf < 4; ++nf) {
          int cl = (w >> 1) * 64 + nf * 16 + (lane & 15);
          float v = acc[mf][nf][j] + breg[nf];
          C[(size_t)rg * 128 + cl] = f2bf(v);
          if (DO_STATS) { cs_[nf] += v; cq_[nf] = fmaf(v, v, cq_[nf]); }
        }
      }
    }
  }

  if (DO_STATS) {
    #pragma unroll
    for (int nf = 0; nf < 4; ++nf) {
      float s = cs_[nf], q = cq_[nf];
      s += __shfl_xor(s, 16, 64); s += __shfl_xor(s, 32, 64);
      q += __shfl_xor(q, 16, 64); q += __shfl_xor(q, 32, 64);
      if (c16 == 0) {
        int cl = (w >> 1) * 64 + nf * 16 + (lane & 15);
        atomicAdd(&bnbuf[cl], s);
        atomicAdd(&bnbuf[128 + cl], q);
      }
    }
    __syncthreads();
    atomicAdd(&ssum_out[t], bnbuf[t]);
  }
}

// ================= fused encoder: MLP layer1 -> LDS A-tile -> GEMM =================
__global__ __launch_bounds__(256) void k_enc(
    const float* __restrict__ x, const float* __restrict__ W1,
    const float* __restrict__ b1, const u16* __restrict__ Bp,
    const float* __restrict__ bias, u16* __restrict__ C, int M) {
  __shared__ __align__(16) u16 As[8][2048];
  __shared__ __align__(16) u16 Bs[2][4096];
  __shared__ float xs[448];
  int t = threadIdx.x;
  int lane = t & 63;
  int w = t >> 6;
  int m0 = blockIdx.x * 64;

  auto stageB = [&](int kt, int b) {
    #pragma unroll
    for (int j = 0; j < 2; ++j) {
      int s = (w * 2 + j) * 64 + lane;
      int row = s >> 2;
      int cc = (s & 3) ^ ((row >> 1) & 3);
      const u16* src = Bp + (size_t)row * 256 + kt * 32 + cc * 8;
      GLOAD_LDS16(src, &Bs[b][(w * 2 + j) * 512]);
    }
  };

  stageB(0, 0);
  for (int i = t; i < 448; i += 256) {
    int gi = m0 * 7 + i;
    xs[i] = (gi < M * 7) ? x[gi] : 0.f;
  }
  float w1r[7];
  #pragma unroll
  for (int k = 0; k < 7; ++k) w1r[k] = W1[t * 7 + k];
  float b1r = b1[t];
  __syncthreads();

  // h[nl][t] = relu(x[nl] . W1[t] + b1[t]) -> A-tile (K=256)
  int p = t >> 5;
  int qbase = (t >> 3) & 3;
  int e8 = t & 7;
  for (int nl = 0; nl < 64; ++nl) {
    float acc = b1r;
    #pragma unroll
    for (int k = 0; k < 7; ++k) acc = fmaf(w1r[k], xs[nl * 7 + k], acc);
    acc = fmaxf(acc, 0.f);
    As[p][nl * 32 + (qbase ^ ((nl >> 1) & 3)) * 8 + e8] = f2bf(acc);
  }
  __syncthreads();

  f32x4 acc[2][4] = {};
  int c16 = lane >> 4;
  #pragma unroll
  for (int kt = 0; kt < 8; ++kt) {
    const int b = kt & 1;
    if (kt + 1 < 8) stageB(kt + 1, (kt + 1) & 1);
    bf16x8 af[2], bfr[4];
    #pragma unroll
    for (int mf = 0; mf < 2; ++mf) {
      int row = (w & 1) * 32 + mf * 16 + (lane & 15);
      int cs = c16 ^ ((row >> 1) & 3);
      af[mf] = *(const bf16x8*)&As[kt][row * 32 + cs * 8];
    }
    #pragma unroll
    for (int nf = 0; nf < 4; ++nf) {
      int row = (w >> 1) * 64 + nf * 16 + (lane & 15);
      int cs = c16 ^ ((row >> 1) & 3);
      bfr[nf] = *(const bf16x8*)&Bs[b][row * 32 + cs * 8];
    }
    #pragma unroll
    for (int mf = 0; mf < 2; ++mf)
      #pragma unroll
      for (int nf = 0; nf < 4; ++nf)
        acc[mf][nf] = __builtin_amdgcn_mfma_f32_16x16x32_bf16(af[mf], bfr[nf], acc[mf][nf], 0, 0, 0);
    __syncthreads();
  }

  float breg[4];
  #pragma unroll
  for (int nf = 0; nf < 4; ++nf)
    breg[nf] = bias[(w >> 1) * 64 + nf * 16 + (lane & 15)];
  #pragma unroll
  for (int mf = 0; mf < 2; ++mf) {
    #pragma unroll
    for (int j = 0; j < 4; ++j) {
      int rl = (w & 1) * 32 + mf * 16 + c16 * 4 + j;
      int rg = m0 + rl;
      if (rg < M) {
        #pragma unroll
        for (int nf = 0; nf < 4; ++nf) {
          int cl = (w >> 1) * 64 + nf * 16 + (lane & 15);
          C[(size_t)rg * 128 + cl] = f2bf(acc[mf][nf][j] + breg[nf]);
        }
      }
    }
  }
}

// ================= fused decoder: z5 -> relu(z5@W1+b1) @ W2 + b2 -> out =================
__global__ __launch_bounds__(256) void k_dec(
    const u16* __restrict__ z5, const u16* __restrict__ Bp,
    const float* __restrict__ b1, const float* __restrict__ W2,
    const float* __restrict__ b2, float* __restrict__ out, int M) {
  __shared__ __align__(16) u16 As[4][2048];   // K=128: 4 panels
  __shared__ __align__(16) u16 Bs[2][4096];
  __shared__ float obuf[64][4];               // cross-wave-group partials
  int t = threadIdx.x;
  int lane = t & 63;
  int w = t >> 6;
  int m0 = blockIdx.x * 64;

  auto stageB = [&](int kt, int b) {
    int half = kt >> 2;
    int ktl = kt & 3;
    #pragma unroll
    for (int j = 0; j < 2; ++j) {
      int s = (w * 2 + j) * 64 + lane;
      int row = s >> 2;
      int cc = (s & 3) ^ ((row >> 1) & 3);
      const u16* src = Bp + (size_t)(half * 128 + row) * 128 + ktl * 32 + cc * 8;
      GLOAD_LDS16(src, &Bs[b][(w * 2 + j) * 512]);
    }
  };

  // stage A (4 panels of z5 rows) + B panel 0
  {
    int s = w * 64 + lane;
    int row = s >> 2;
    int cc = (s & 3) ^ ((row >> 1) & 3);
    int rg = m0 + row;
    rg = rg < M ? rg : M - 1;
    #pragma unroll
    for (int p = 0; p < 4; ++p) {
      const u16* src = z5 + (size_t)rg * 128 + p * 32 + cc * 8;
      GLOAD_LDS16(src, &As[p][w * 512]);
    }
  }
  stageB(0, 0);

  float w2r[2][4][4], b1r[2][4];
  #pragma unroll
  for (int h = 0; h < 2; ++h) {
    #pragma unroll
    for (int nf = 0; nf < 4; ++nf) {
      int col = h * 128 + (w >> 1) * 64 + nf * 16 + (lane & 15);
      b1r[h][nf] = b1[col];
      #pragma unroll
      for (int o = 0; o < 4; ++o) w2r[h][o][nf] = W2[o * 256 + col];
    }
  }
  __syncthreads();

  f32x4 acc[2][4] = {};
  float po[2][4][4] = {};
  int c16 = lane >> 4;
  #pragma unroll
  for (int kt = 0; kt < 8; ++kt) {
    const int b = kt & 1;
    if (kt + 1 < 8) stageB(kt + 1, (kt + 1) & 1);
    bf16x8 af[2], bfr[4];
    #pragma unroll
    for (int mf = 0; mf < 2; ++mf) {
      int row = (w & 1) * 32 + mf * 16 + (lane & 15);
      int cs = c16 ^ ((row >> 1) & 3);
      af[mf] = *(const bf16x8*)&As[kt & 3][row * 32 + cs * 8];
    }
    #pragma unroll
    for (int nf = 0; nf < 4; ++nf) {
      int row = (w >> 1) * 64 + nf * 16 + (lane & 15);
      int cs = c16 ^ ((row >> 1) & 3);
      bfr[nf] = *(const bf16x8*)&Bs[b][row * 32 + cs * 8];
    }
    #pragma unroll
    for (int mf = 0; mf < 2; ++mf)
      #pragma unroll
      for (int nf = 0; nf < 4; ++nf)
        acc[mf][nf] = __builtin_amdgcn_mfma_f32_16x16x32_bf16(af[mf], bfr[nf], acc[mf][nf], 0, 0, 0);
    __syncthreads();
    if (kt == 3 || kt == 7) {
      int h = kt >> 2;
      #pragma unroll
      for (int mf = 0; mf < 2; ++mf)
        #pragma unroll
        for (int j = 0; j < 4; ++j)
          #pragma unroll
          for (int nf = 0; nf < 4; ++nf) {
            float hv = fmaxf(acc[mf][nf][j] + b1r[h][nf], 0.f);
            #pragma unroll
            for (int o = 0; o < 4; ++o) po[mf][j][o] = fmaf(hv, w2r[h][o][nf], po[mf][j][o]);
          }
      #pragma unroll
      for (int mf = 0; mf < 2; ++mf)
        #pragma unroll
        for (int nf = 0; nf < 4; ++nf)
          acc[mf][nf] = (f32x4){0.f, 0.f, 0.f, 0.f};
    }
  }

  // reduce po across the 16 lanes of each col-group (butterfly -> all lanes hold sum)
  #pragma unroll
  for (int mf = 0; mf < 2; ++mf)
    #pragma unroll
    for (int j = 0; j < 4; ++j)
      #pragma unroll
      for (int o = 0; o < 4; ++o) {
        float v = po[mf][j][o];
        v += __shfl_xor(v, 1, 16);
        v += __shfl_xor(v, 2, 16);
        v += __shfl_xor(v, 4, 16);
        v += __shfl_xor(v, 8, 16);
        po[mf][j][o] = v;
      }

  // cross-wave-group combine: group 0 (cols 0..63 of each half) parks partials in LDS,
  // group 1 (cols 64..127) adds and stores.
  int g = w >> 1;
  if (g == 0 && (lane & 15) == 0) {
    #pragma unroll
    for (int mf = 0; mf < 2; ++mf)
      #pragma unroll
      for (int j = 0; j < 4; ++j) {
        int rl = (w & 1) * 32 + mf * 16 + c16 * 4 + j;
        #pragma unroll
        for (int o = 0; o < 4; ++o) obuf[rl][o] = po[mf][j][o];
      }
  }
  __syncthreads();
  if (g == 1 && (lane & 15) == 0) {
    #pragma unroll
    for (int mf = 0; mf < 2; ++mf)
      #pragma unroll
      for (int j = 0; j < 4; ++j) {
        int rl = (w & 1) * 32 + mf * 16 + c16 * 4 + j;
        int rg = m0 + rl;
        if (rg < M) {
          #pragma unroll
          for (int o = 0; o < 4; ++o)
            out[(size_t)rg * 4 + o] = obuf[rl][o] + po[mf][j][o] + b2[o];
        }
      }
  }
}

// ---------------- launch ----------------
extern "C" void kernel_launch(void* const* d_in, const int* in_sizes, int n_in,
                              void* d_out, int out_size, void* d_ws, size_t ws_size,
                              hipStream_t stream) {
  const float* x     = (const float*)d_in[0];
  const int*   ei    = (const int*)d_in[1];
  const float* encW1 = (const float*)d_in[2];
  const float* encb1 = (const float*)d_in[3];
  const float* encW2 = (const float*)d_in[4];
  const float* encb2 = (const float*)d_in[5];
  const float* Wl    = (const float*)d_in[6];
  const float* bl    = (const float*)d_in[7];
  const float* Wr    = (const float*)d_in[8];
  const float* gamma = (const float*)d_in[9];
  const float* beta  = (const float*)d_in[10];
  const float* decW1 = (const float*)d_in[11];
  const float* decb1 = (const float*)d_in[12];
  const float* decW2 = (const float*)d_in[13];
  const float* decb2 = (const float*)d_in[14];
  float* out = (float*)d_out;

  const int M = M_NODES, E = E_EDGES;
  char* p = (char*)d_ws;
  auto take = [&](size_t b) { char* r = p; p += (b + 255) & ~(size_t)255; return r; };
  u16* zA     = (u16*)take((size_t)M * 128 * 2);
  u16* zB     = (u16*)take((size_t)M * 128 * 2);
  u16* Bpack  = (u16*)take((size_t)229376 * 2);
  int* cnt    = (int*)take((size_t)M * 4);
  int* bucket = (int*)take((size_t)M * BKT * 4);
  float* ssums = (float*)take(4 * 256 * 4);

  const int* srcp = ei;
  const int* dstp = ei + E;

  k_prep<<<896, 256, 0, stream>>>(encW2, Wl, Wr, decW1, Bpack);
  hipMemsetAsync(cnt, 0, (size_t)M * 4, stream);
  hipMemsetAsync(ssums, 0, 4 * 256 * 4, stream);
  k_place<<<(E + 255) / 256, 256, 0, stream>>>(srcp, dstp, cnt, bucket, E);

  const int GX = (M + 63) / 64;

  k_enc<<<GX, 256, 0, stream>>>(x, encW1, encb1, Bpack, encb2, zA, M);

  // conv 0: no input transform, collect stats
  k_conv<0, 1><<<GX, 256, 0, stream>>>(zA, cnt, bucket, nullptr, nullptr, nullptr,
                                       Bpack + 32768, bl, zB, M, ssums);
  // conv 1..3: BN(prev stats) on input, collect stats
  k_conv<1, 1><<<GX, 256, 0, stream>>>(zB, cnt, bucket, ssums, gamma, beta,
                                       Bpack + 32768 + 32768, bl + 128, zA, M, ssums + 256);
  k_conv<1, 1><<<GX, 256, 0, stream>>>(zA, cnt, bucket, ssums + 256, gamma + 128, beta + 128,
                                       Bpack + 32768 + 2 * 32768, bl + 256, zB, M, ssums + 512);
  k_conv<1, 1><<<GX, 256, 0, stream>>>(zB, cnt, bucket, ssums + 512, gamma + 256, beta + 256,
                                       Bpack + 32768 + 3 * 32768, bl + 384, zA, M, ssums + 768);
  // conv 4: BN(stats 3), no stats
  k_conv<1, 0><<<GX, 256, 0, stream>>>(zA, cnt, bucket, ssums + 768, gamma + 384, beta + 384,
                                       Bpack + 32768 + 4 * 32768, bl + 512, zB, M, nullptr);

  k_dec<<<GX, 256, 0, stream>>>(zB, Bpack + 196608, decb1, decW2, decb2, out, M);
}

// Round 9
// 561.394 us; speedup vs baseline: 1.1870x; 1.1870x over previous
//
#include <hip/hip_runtime.h>

using u16 = unsigned short;
using u32 = unsigned int;

#define M_NODES 50000
#define E_EDGES 600000
#define EPS_BN 1e-5f
#define BKT 48

typedef __attribute__((ext_vector_type(8))) short bf16x8;
typedef __attribute__((ext_vector_type(4))) float f32x4;

__device__ __forceinline__ float bf2f(u16 v) {
  union { u32 u; float f; } x; x.u = ((u32)v) << 16; return x.f;
}
__device__ __forceinline__ float lo16f(u32 v) {
  union { u32 u; float f; } x; x.u = v << 16; return x.f;
}
__device__ __forceinline__ float hi16f(u32 v) {
  union { u32 u; float f; } x; x.u = v & 0xffff0000u; return x.f;
}
__device__ __forceinline__ u16 f2bf(float f) {
  union { float f; u32 u; } x; x.f = f;
  u32 r = x.u + 0x7fffu + ((x.u >> 16) & 1u);
  return (u16)(r >> 16);
}

#define GLOAD_LDS16(g, l)                                                        \
  __builtin_amdgcn_global_load_lds((const __attribute__((address_space(1))) void*)(g), \
                                   (__attribute__((address_space(3))) void*)(l), 16, 0, 0)

// ---------------- bucket build ----------------
__global__ void k_place(const int* __restrict__ src, const int* __restrict__ dst,
                        int* __restrict__ cnt, int* __restrict__ bucket, int n) {
  int e = blockIdx.x * blockDim.x + threadIdx.x;
  if (e < n) {
    int d = dst[e];
    int p = atomicAdd(&cnt[d], 1);
    if (p < BKT) bucket[d * BKT + p] = src[e];
  }
}

// ---------------- weight prep ----------------
// [0,32768) encW2 [128][256]; [32768+i*32768) conv i [128][256]=[Wl|Wr]; [196608,229376) decW1 [256][128]
__global__ __launch_bounds__(256) void k_prep(const float* __restrict__ encW2,
                                              const float* __restrict__ Wl,
                                              const float* __restrict__ Wr,
                                              const float* __restrict__ decW1,
                                              u16* __restrict__ Bp) {
  int e = blockIdx.x * 256 + threadIdx.x;
  float v;
  if (e < 32768) {
    v = encW2[e];
  } else if (e < 196608) {
    int r = e - 32768;
    int i = r >> 15;
    int rr = r & 32767;
    int n = rr >> 8;
    int k = rr & 255;
    v = (k < 128) ? Wl[i * 16384 + n * 128 + k] : Wr[i * 16384 + n * 128 + (k - 128)];
  } else {
    v = decW1[e - 196608];
  }
  Bp[e] = f2bf(v);
}

// ---------------- out init: out[n][o] = b2[o] ----------------
__global__ void k_outinit(float* __restrict__ out, const float* __restrict__ b2, int n4) {
  int i = blockIdx.x * 256 + threadIdx.x;
  if (i < n4) out[i] = b2[i & 3];
}

// ---------------- fused mean-aggregation (+BN+relu of previous layer) — R5-proven ----------------
template <int TRANS>
__global__ __launch_bounds__(256) void k_agg(const u16* __restrict__ z,
                                             const int* __restrict__ cnt,
                                             const int* __restrict__ bucket,
                                             const float* __restrict__ ssum,
                                             const float* __restrict__ gamma,
                                             const float* __restrict__ beta,
                                             u16* __restrict__ mean,
                                             u16* __restrict__ zp, int M) {
  __shared__ float s_sc[256];
  int t = threadIdx.x;
  if (TRANS) {
    if (t < 128) {
      float m = ssum[t] * (1.0f / M_NODES);
      float var = ssum[128 + t] * (1.0f / M_NODES) - m * m;
      float s = gamma[t] * rsqrtf(var + EPS_BN);
      s_sc[t] = s;
      s_sc[128 + t] = beta[t] - m * s;
    }
    __syncthreads();
  }
  int node = blockIdx.x * 4 + (t >> 6);
  int lane = t & 63;
  int slot = lane >> 4;
  int fc = lane & 15;
  float sreg[8], treg[8];
  if (TRANS) {
    #pragma unroll
    for (int i = 0; i < 8; ++i) { sreg[i] = s_sc[fc * 8 + i]; treg[i] = s_sc[128 + fc * 8 + i]; }
  }
  int deg = cnt[node];
  int nd = deg < BKT ? deg : BKT;
  const int* bk = bucket + (size_t)node * BKT;
  float a[8] = {};
  for (int j = slot; j < nd; j += 4) {
    int s = bk[j];
    uint4 v = *(const uint4*)(z + (size_t)s * 128 + fc * 8);
    float f[8] = {lo16f(v.x), hi16f(v.x), lo16f(v.y), hi16f(v.y),
                  lo16f(v.z), hi16f(v.z), lo16f(v.w), hi16f(v.w)};
    #pragma unroll
    for (int i = 0; i < 8; ++i) {
      float vv = TRANS ? fmaxf(fmaf(f[i], sreg[i], treg[i]), 0.f) : f[i];
      a[i] += vv;
    }
  }
  #pragma unroll
  for (int i = 0; i < 8; ++i) {
    a[i] += __shfl_xor(a[i], 16, 64);
    a[i] += __shfl_xor(a[i], 32, 64);
  }
  if (slot == 0) {
    float inv = 1.0f / (float)(deg > 1 ? deg : 1);
    uint4 r;
    r.x = (u32)f2bf(a[0] * inv) | ((u32)f2bf(a[1] * inv) << 16);
    r.y = (u32)f2bf(a[2] * inv) | ((u32)f2bf(a[3] * inv) << 16);
    r.z = (u32)f2bf(a[4] * inv) | ((u32)f2bf(a[5] * inv) << 16);
    r.w = (u32)f2bf(a[6] * inv) | ((u32)f2bf(a[7] * inv) << 16);
    *(uint4*)(mean + (size_t)node * 128 + fc * 8) = r;
  }
  if (TRANS && slot == 1) {
    uint4 v = *(const uint4*)(z + (size_t)node * 128 + fc * 8);
    float f[8] = {lo16f(v.x), hi16f(v.x), lo16f(v.y), hi16f(v.y),
                  lo16f(v.z), hi16f(v.z), lo16f(v.w), hi16f(v.w)};
    u16 o[8];
    #pragma unroll
    for (int i = 0; i < 8; ++i) o[i] = f2bf(fmaxf(fmaf(f[i], sreg[i], treg[i]), 0.f));
    uint4 r;
    r.x = (u32)o[0] | ((u32)o[1] << 16);
    r.y = (u32)o[2] | ((u32)o[3] << 16);
    r.z = (u32)o[4] | ((u32)o[5] << 16);
    r.w = (u32)o[6] | ((u32)o[7] << 16);
    *(uint4*)(zp + (size_t)node * 128 + fc * 8) = r;
  }
}

// ================= all-resident GEMM: BM=32 x BN=64, K=256, everything staged up-front ===========
// A panels 0-3 from A1 (K 0..127), 4-7 from A2 (K 128..255); B = Bp[n0c+row][256].
// Per wave: 4 A-issues + 8 B-issues back-to-back (12 KB in flight), ONE barrier, barrier-free K-loop.
template <int DO_STATS>
__global__ __launch_bounds__(256) void k_gemm32(
    const u16* __restrict__ A1, const u16* __restrict__ A2,
    const u16* __restrict__ Bp, const float* __restrict__ bias,
    u16* __restrict__ C, int M, float* __restrict__ ssum_out) {
  __shared__ __align__(16) u16 As[8][1024];   // 8 panels x (32 rows x 32)
  __shared__ __align__(16) u16 Bs[8][2048];   // 8 panels x (64 rows x 32)
  __shared__ __align__(16) u16 Cs[32][64];
  __shared__ float bnbuf[128];
  int t = threadIdx.x;
  int lane = t & 63;
  int w = t >> 6;
  int m0 = blockIdx.x * 32;
  int n0c = blockIdx.y * 64;

  // ---- A: 4 issues/wave ----
  #pragma unroll
  for (int j = 0; j < 4; ++j) {
    int s = (w * 4 + j) * 64 + lane;      // 0..1023 16B-slot
    int p = s >> 7;                        // panel
    int sp = s & 127;
    int row = sp >> 2;
    int cc = (sp & 3) ^ ((row >> 1) & 3);
    int rg = m0 + row;
    rg = rg < M ? rg : M - 1;
    const u16* src = (p < 4 ? A1 + (size_t)rg * 128 + p * 32
                            : A2 + (size_t)rg * 128 + (p - 4) * 32) + cc * 8;
    GLOAD_LDS16(src, &((u16*)As)[s * 8]);
  }
  // ---- B: 8 issues/wave ----
  #pragma unroll
  for (int j = 0; j < 8; ++j) {
    int s = (w * 8 + j) * 64 + lane;      // 0..2047
    int p = s >> 8;
    int sp = s & 255;
    int row = sp >> 2;
    int cc = (sp & 3) ^ ((row >> 1) & 3);
    const u16* src = Bp + (size_t)(n0c + row) * 256 + p * 32 + cc * 8;
    GLOAD_LDS16(src, &((u16*)Bs)[s * 8]);
  }
  __syncthreads();   // single drain: all 12 issues/wave complete

  // ---- barrier-free K-loop ----
  f32x4 acc[2] = {};
  int c16 = lane >> 4;
  int fc = lane & 15;
  #pragma unroll
  for (int kt = 0; kt < 8; ++kt) {
    bf16x8 af[2], bf;
    #pragma unroll
    for (int mf = 0; mf < 2; ++mf) {
      int row = mf * 16 + fc;
      int cs = c16 ^ ((row >> 1) & 3);
      af[mf] = *(const bf16x8*)&As[kt][row * 32 + cs * 8];
    }
    {
      int row = w * 16 + fc;
      int cs = c16 ^ ((row >> 1) & 3);
      bf = *(const bf16x8*)&Bs[kt][row * 32 + cs * 8];
    }
    #pragma unroll
    for (int mf = 0; mf < 2; ++mf)
      acc[mf] = __builtin_amdgcn_mfma_f32_16x16x32_bf16(af[mf], bf, acc[mf], 0, 0, 0);
  }

  // ---- epilogue: bias, stats, C -> LDS -> coalesced stream ----
  float breg = bias[n0c + w * 16 + fc];
  float cs_ = 0.f, cq_ = 0.f;
  #pragma unroll
  for (int mf = 0; mf < 2; ++mf) {
    #pragma unroll
    for (int j = 0; j < 4; ++j) {
      int row = mf * 16 + c16 * 4 + j;
      float v = acc[mf][j] + breg;
      Cs[row][w * 16 + fc] = f2bf(v);
      if (DO_STATS && m0 + row < M) { cs_ += v; cq_ = fmaf(v, v, cq_); }
    }
  }
  if (DO_STATS) {
    cs_ += __shfl_xor(cs_, 16, 64); cs_ += __shfl_xor(cs_, 32, 64);
    cq_ += __shfl_xor(cq_, 16, 64); cq_ += __shfl_xor(cq_, 32, 64);
    if (lane < 16) {
      bnbuf[w * 16 + lane] = cs_;
      bnbuf[64 + w * 16 + lane] = cq_;
    }
  }
  __syncthreads();
  {
    int row = t >> 3;
    int rg = m0 + row;
    if (rg < M) {
      uint4 v = *(const uint4*)&Cs[row][(t & 7) * 8];
      *(uint4*)(C + (size_t)rg * 128 + n0c + (t & 7) * 8) = v;
    }
  }
  if (DO_STATS && t < 128) {
    float v = bnbuf[t];
    int idx = (t < 64) ? (n0c + t) : (128 + n0c + (t - 64));
    atomicAdd(&ssum_out[idx], v);
  }
}

// ================= fused encoder: x-MLP -> LDS A-tile -> all-resident GEMM =================
__global__ __launch_bounds__(256) void k_enc(
    const float* __restrict__ x, const float* __restrict__ W1,
    const float* __restrict__ b1, const u16* __restrict__ Bp,
    const float* __restrict__ bias, u16* __restrict__ C, int M) {
  __shared__ __align__(16) u16 As[8][1024];
  __shared__ __align__(16) u16 Bs[8][2048];
  __shared__ __align__(16) u16 Cs[32][64];
  __shared__ float xs[224];
  int t = threadIdx.x;
  int lane = t & 63;
  int w = t >> 6;
  int m0 = blockIdx.x * 32;
  int n0c = blockIdx.y * 64;

  // B issues first (fly during A compute)
  #pragma unroll
  for (int j = 0; j < 8; ++j) {
    int s = (w * 8 + j) * 64 + lane;
    int p = s >> 8;
    int sp = s & 255;
    int row = sp >> 2;
    int cc = (sp & 3) ^ ((row >> 1) & 3);
    const u16* src = Bp + (size_t)(n0c + row) * 256 + p * 32 + cc * 8;
    GLOAD_LDS16(src, &((u16*)Bs)[s * 8]);
  }
  // x tile
  for (int i = t; i < 224; i += 256) {
    int gi = m0 * 7 + i;
    xs[i] = (gi < M * 7) ? x[gi] : 0.f;
  }
  float w1r[7];
  #pragma unroll
  for (int k = 0; k < 7; ++k) w1r[k] = W1[t * 7 + k];
  float b1r = b1[t];
  __syncthreads();

  // h[r][t] -> A-tile swizzled
  int p = t >> 5;
  int cq = (t & 31) >> 3;
  int e8 = t & 7;
  for (int r = 0; r < 32; ++r) {
    float acc = b1r;
    #pragma unroll
    for (int k = 0; k < 7; ++k) acc = fmaf(w1r[k], xs[r * 7 + k], acc);
    As[p][r * 32 + (cq ^ ((r >> 1) & 3)) * 8 + e8] = f2bf(fmaxf(acc, 0.f));
  }
  __syncthreads();

  f32x4 acc[2] = {};
  int c16 = lane >> 4;
  int fc = lane & 15;
  #pragma unroll
  for (int kt = 0; kt < 8; ++kt) {
    bf16x8 af[2], bf;
    #pragma unroll
    for (int mf = 0; mf < 2; ++mf) {
      int row = mf * 16 + fc;
      int cs = c16 ^ ((row >> 1) & 3);
      af[mf] = *(const bf16x8*)&As[kt][row * 32 + cs * 8];
    }
    {
      int row = w * 16 + fc;
      int cs = c16 ^ ((row >> 1) & 3);
      bf = *(const bf16x8*)&Bs[kt][row * 32 + cs * 8];
    }
    #pragma unroll
    for (int mf = 0; mf < 2; ++mf)
      acc[mf] = __builtin_amdgcn_mfma_f32_16x16x32_bf16(af[mf], bf, acc[mf], 0, 0, 0);
  }

  float breg = bias[n0c + w * 16 + fc];
  #pragma unroll
  for (int mf = 0; mf < 2; ++mf)
    #pragma unroll
    for (int j = 0; j < 4; ++j) {
      int row = mf * 16 + c16 * 4 + j;
      Cs[row][w * 16 + fc] = f2bf(acc[mf][j] + breg);
    }
  __syncthreads();
  {
    int row = t >> 3;
    int rg = m0 + row;
    if (rg < M) {
      uint4 v = *(const uint4*)&Cs[row][(t & 7) * 8];
      *(uint4*)(C + (size_t)rg * 128 + n0c + (t & 7) * 8) = v;
    }
  }
}

// ================= fused decoder: z5 -> relu(z5@W1+b1) . W2 -> atomicAdd out =================
// grid (1563, 2): y-block covers hidden cols yb*128..+127. BM=32, K=128 (4 panels).
__global__ __launch_bounds__(256) void k_dec(
    const u16* __restrict__ z5, const u16* __restrict__ Bpd,
    const float* __restrict__ b1, const float* __restrict__ W2,
    float* __restrict__ out, int M) {
  __shared__ __align__(16) u16 As[4][1024];
  __shared__ __align__(16) u16 Bs[4][4096];   // 4 panels x (128 rows x 32)
  __shared__ float obuf[128];                  // [32 rows][4 o]
  int t = threadIdx.x;
  int lane = t & 63;
  int w = t >> 6;
  int m0 = blockIdx.x * 32;
  int hb = blockIdx.y * 128;

  // A: 2 issues/wave
  #pragma unroll
  for (int j = 0; j < 2; ++j) {
    int s = (w * 2 + j) * 64 + lane;      // 0..511
    int p = s >> 7;
    int sp = s & 127;
    int row = sp >> 2;
    int cc = (sp & 3) ^ ((row >> 1) & 3);
    int rg = m0 + row;
    rg = rg < M ? rg : M - 1;
    const u16* src = z5 + (size_t)rg * 128 + p * 32 + cc * 8;
    GLOAD_LDS16(src, &((u16*)As)[s * 8]);
  }
  // B: 8 issues/wave
  #pragma unroll
  for (int j = 0; j < 8; ++j) {
    int s = (w * 8 + j) * 64 + lane;      // 0..2047
    int p = s >> 9;
    int sp = s & 511;
    int row = sp >> 2;
    int cc = (sp & 3) ^ ((row >> 1) & 3);
    const u16* src = Bpd + (size_t)(hb + row) * 128 + p * 32 + cc * 8;
    GLOAD_LDS16(src, &((u16*)Bs)[s * 8]);
  }
  if (t < 128) obuf[t] = 0.f;
  __syncthreads();

  int c16 = lane >> 4;
  int fc = lane & 15;
  f32x4 acc[2][2] = {};
  #pragma unroll
  for (int kt = 0; kt < 4; ++kt) {
    bf16x8 af[2], bf[2];
    #pragma unroll
    for (int mf = 0; mf < 2; ++mf) {
      int row = mf * 16 + fc;
      int cs = c16 ^ ((row >> 1) & 3);
      af[mf] = *(const bf16x8*)&As[kt][row * 32 + cs * 8];
    }
    #pragma unroll
    for (int nf = 0; nf < 2; ++nf) {
      int row = w * 32 + nf * 16 + fc;
      int cs = c16 ^ ((row >> 1) & 3);
      bf[nf] = *(const bf16x8*)&Bs[kt][row * 32 + cs * 8];
    }
    #pragma unroll
    for (int mf = 0; mf < 2; ++mf)
      #pragma unroll
      for (int nf = 0; nf < 2; ++nf)
        acc[mf][nf] = __builtin_amdgcn_mfma_f32_16x16x32_bf16(af[mf], bf[nf], acc[mf][nf], 0, 0, 0);
  }

  float b1r[2], w2r[4][2];
  #pragma unroll
  for (int nf = 0; nf < 2; ++nf) {
    int col = hb + w * 32 + nf * 16 + fc;
    b1r[nf] = b1[col];
    #pragma unroll
    for (int o = 0; o < 4; ++o) w2r[o][nf] = W2[o * 256 + col];
  }
  float po[2][4][4] = {};
  #pragma unroll
  for (int mf = 0; mf < 2; ++mf)
    #pragma unroll
    for (int j = 0; j < 4; ++j)
      #pragma unroll
      for (int nf = 0; nf < 2; ++nf) {
        float hv = fmaxf(acc[mf][nf][j] + b1r[nf], 0.f);
        #pragma unroll
        for (int o = 0; o < 4; ++o) po[mf][j][o] = fmaf(hv, w2r[o][nf], po[mf][j][o]);
      }
  #pragma unroll
  for (int mf = 0; mf < 2; ++mf)
    #pragma unroll
    for (int j = 0; j < 4; ++j)
      #pragma unroll
      for (int o = 0; o < 4; ++o) {
        float v = po[mf][j][o];
        v += __shfl_xor(v, 1, 16);
        v += __shfl_xor(v, 2, 16);
        v += __shfl_xor(v, 4, 16);
        po[mf][j][o] = v + __shfl_xor(v, 8, 16);
      }
  if (fc == 0) {
    #pragma unroll
    for (int mf = 0; mf < 2; ++mf)
      #pragma unroll
      for (int j = 0; j < 4; ++j) {
        int row = mf * 16 + c16 * 4 + j;
        #pragma unroll
        for (int o = 0; o < 4; ++o) atomicAdd(&obuf[row * 4 + o], po[mf][j][o]);
      }
  }
  __syncthreads();
  if (t < 128) {
    int row = t >> 2;
    int rg = m0 + row;
    if (rg < M) atomicAdd(out + (size_t)rg * 4 + (t & 3), obuf[t]);
  }
}

// ---------------- launch ----------------
extern "C" void kernel_launch(void* const* d_in, const int* in_sizes, int n_in,
                              void* d_out, int out_size, void* d_ws, size_t ws_size,
                              hipStream_t stream) {
  const float* x     = (const float*)d_in[0];
  const int*   ei    = (const int*)d_in[1];
  const float* encW1 = (const float*)d_in[2];
  const float* encb1 = (const float*)d_in[3];
  const float* encW2 = (const float*)d_in[4];
  const float* encb2 = (const float*)d_in[5];
  const float* Wl    = (const float*)d_in[6];
  const float* bl    = (const float*)d_in[7];
  const float* Wr    = (const float*)d_in[8];
  const float* gamma = (const float*)d_in[9];
  const float* beta  = (const float*)d_in[10];
  const float* decW1 = (const float*)d_in[11];
  const float* decb1 = (const float*)d_in[12];
  const float* decW2 = (const float*)d_in[13];
  const float* decb2 = (const float*)d_in[14];
  float* out = (float*)d_out;

  const int M = M_NODES, E = E_EDGES;
  char* p = (char*)d_ws;
  auto take = [&](size_t b) { char* r = p; p += (b + 255) & ~(size_t)255; return r; };
  u16* zA     = (u16*)take((size_t)M * 128 * 2);
  u16* zB     = (u16*)take((size_t)M * 128 * 2);
  u16* zP     = (u16*)take((size_t)M * 128 * 2);
  u16* mean   = (u16*)take((size_t)M * 128 * 2);
  u16* Bpack  = (u16*)take((size_t)229376 * 2);
  int* cnt    = (int*)take((size_t)M * 4);
  int* bucket = (int*)take((size_t)M * BKT * 4);
  float* ssums = (float*)take(4 * 256 * 4);

  const int* srcp = ei;
  const int* dstp = ei + E;

  k_prep<<<896, 256, 0, stream>>>(encW2, Wl, Wr, decW1, Bpack);
  hipMemsetAsync(cnt, 0, (size_t)M * 4, stream);
  hipMemsetAsync(ssums, 0, 4 * 256 * 4, stream);
  k_outinit<<<(M * 4 + 255) / 256, 256, 0, stream>>>(out, decb2, M * 4);
  k_place<<<(E + 255) / 256, 256, 0, stream>>>(srcp, dstp, cnt, bucket, E);

  const int GX = (M + 31) / 32;   // 1563
  dim3 gg(GX, 2);

  k_enc<<<gg, 256, 0, stream>>>(x, encW1, encb1, Bpack, encb2, zA, M);

  u16* cur = zA;
  u16* nxt = zB;
  for (int i = 0; i < 5; ++i) {
    if (i == 0) {
      k_agg<0><<<M / 4, 256, 0, stream>>>(cur, cnt, bucket, nullptr, nullptr, nullptr,
                                          mean, zP, M);
    } else {
      k_agg<1><<<M / 4, 256, 0, stream>>>(cur, cnt, bucket, ssums + (i - 1) * 256,
                                          gamma + (size_t)(i - 1) * 128,
                                          beta + (size_t)(i - 1) * 128, mean, zP, M);
    }
    const u16* A2 = (i == 0) ? cur : zP;
    if (i < 4) {
      k_gemm32<1><<<gg, 256, 0, stream>>>(mean, A2, Bpack + 32768 + i * 32768,
                                          bl + (size_t)i * 128, nxt, M, ssums + i * 256);
    } else {
      k_gemm32<0><<<gg, 256, 0, stream>>>(mean, A2, Bpack + 32768 + i * 32768,
                                          bl + (size_t)i * 128, nxt, M, nullptr);
    }
    u16* tswap = cur; cur = nxt; nxt = tswap;
  }

  k_dec<<<gg, 256, 0, stream>>>(cur, Bpack + 196608, decb1, decW2, out, M);
}

// Round 10
// 380.929 us; speedup vs baseline: 1.7494x; 1.4738x over previous
//
#include <hip/hip_runtime.h>

using u16 = unsigned short;
using u32 = unsigned int;

#define M_NODES 50000
#define E_EDGES 600000
#define EPS_BN 1e-5f
#define BKT 48

typedef __attribute__((ext_vector_type(8))) short bf16x8;
typedef __attribute__((ext_vector_type(4))) float f32x4;

__device__ __forceinline__ float bf2f(u16 v) {
  union { u32 u; float f; } x; x.u = ((u32)v) << 16; return x.f;
}
__device__ __forceinline__ float lo16f(u32 v) {
  union { u32 u; float f; } x; x.u = v << 16; return x.f;
}
__device__ __forceinline__ float hi16f(u32 v) {
  union { u32 u; float f; } x; x.u = v & 0xffff0000u; return x.f;
}
__device__ __forceinline__ u16 f2bf(float f) {
  union { float f; u32 u; } x; x.f = f;
  u32 r = x.u + 0x7fffu + ((x.u >> 16) & 1u);
  return (u16)(r >> 16);
}

#define GLOAD_LDS16(g, l)                                                        \
  __builtin_amdgcn_global_load_lds((const __attribute__((address_space(1))) void*)(g), \
                                   (__attribute__((address_space(3))) void*)(l), 16, 0, 0)

// ---------------- bucket build ----------------
__global__ void k_place(const int* __restrict__ src, const int* __restrict__ dst,
                        int* __restrict__ cnt, int* __restrict__ bucket, int n) {
  int e = blockIdx.x * blockDim.x + threadIdx.x;
  if (e < n) {
    int d = dst[e];
    int p = atomicAdd(&cnt[d], 1);
    if (p < BKT) bucket[d * BKT + p] = src[e];
  }
}

// ---------------- weight prep ----------------
// [0,32768) encW2 [128][256]; [32768+i*32768) conv i [128][256]=[Wl|Wr]; [196608,229376) decW1 [256][128]
__global__ __launch_bounds__(256) void k_prep(const float* __restrict__ encW2,
                                              const float* __restrict__ Wl,
                                              const float* __restrict__ Wr,
                                              const float* __restrict__ decW1,
                                              u16* __restrict__ Bp) {
  int e = blockIdx.x * 256 + threadIdx.x;
  float v;
  if (e < 32768) {
    v = encW2[e];
  } else if (e < 196608) {
    int r = e - 32768;
    int i = r >> 15;
    int rr = r & 32767;
    int n = rr >> 8;
    int k = rr & 255;
    v = (k < 128) ? Wl[i * 16384 + n * 128 + k] : Wr[i * 16384 + n * 128 + (k - 128)];
  } else {
    v = decW1[e - 196608];
  }
  Bp[e] = f2bf(v);
}

// ---------------- fused mean-aggregation (+BN+relu of previous layer) ----------------
template <int TRANS>
__global__ __launch_bounds__(256) void k_agg(const u16* __restrict__ z,
                                             const int* __restrict__ cnt,
                                             const int* __restrict__ bucket,
                                             const float* __restrict__ ssum,
                                             const float* __restrict__ gamma,
                                             const float* __restrict__ beta,
                                             u16* __restrict__ mean,
                                             u16* __restrict__ zp, int M) {
  __shared__ float s_sc[256];
  int t = threadIdx.x;
  if (TRANS) {
    if (t < 128) {
      float m = ssum[t] * (1.0f / M_NODES);
      float var = ssum[128 + t] * (1.0f / M_NODES) - m * m;
      float s = gamma[t] * rsqrtf(var + EPS_BN);
      s_sc[t] = s;
      s_sc[128 + t] = beta[t] - m * s;
    }
    __syncthreads();
  }
  int node = blockIdx.x * 4 + (t >> 6);
  int lane = t & 63;
  int slot = lane >> 4;
  int fc = lane & 15;
  float sreg[8], treg[8];
  if (TRANS) {
    #pragma unroll
    for (int i = 0; i < 8; ++i) { sreg[i] = s_sc[fc * 8 + i]; treg[i] = s_sc[128 + fc * 8 + i]; }
  }
  int deg = cnt[node];
  int nd = deg < BKT ? deg : BKT;
  const int* bk = bucket + (size_t)node * BKT;
  float a[8] = {};
  for (int j = slot; j < nd; j += 4) {
    int s = bk[j];
    uint4 v = *(const uint4*)(z + (size_t)s * 128 + fc * 8);
    float f[8] = {lo16f(v.x), hi16f(v.x), lo16f(v.y), hi16f(v.y),
                  lo16f(v.z), hi16f(v.z), lo16f(v.w), hi16f(v.w)};
    #pragma unroll
    for (int i = 0; i < 8; ++i) {
      float vv = TRANS ? fmaxf(fmaf(f[i], sreg[i], treg[i]), 0.f) : f[i];
      a[i] += vv;
    }
  }
  #pragma unroll
  for (int i = 0; i < 8; ++i) {
    a[i] += __shfl_xor(a[i], 16, 64);
    a[i] += __shfl_xor(a[i], 32, 64);
  }
  if (slot == 0) {
    float inv = 1.0f / (float)(deg > 1 ? deg : 1);
    uint4 r;
    r.x = (u32)f2bf(a[0] * inv) | ((u32)f2bf(a[1] * inv) << 16);
    r.y = (u32)f2bf(a[2] * inv) | ((u32)f2bf(a[3] * inv) << 16);
    r.z = (u32)f2bf(a[4] * inv) | ((u32)f2bf(a[5] * inv) << 16);
    r.w = (u32)f2bf(a[6] * inv) | ((u32)f2bf(a[7] * inv) << 16);
    *(uint4*)(mean + (size_t)node * 128 + fc * 8) = r;
  }
  if (TRANS && slot == 1) {
    uint4 v = *(const uint4*)(z + (size_t)node * 128 + fc * 8);
    float f[8] = {lo16f(v.x), hi16f(v.x), lo16f(v.y), hi16f(v.y),
                  lo16f(v.z), hi16f(v.z), lo16f(v.w), hi16f(v.w)};
    u16 o[8];
    #pragma unroll
    for (int i = 0; i < 8; ++i) o[i] = f2bf(fmaxf(fmaf(f[i], sreg[i], treg[i]), 0.f));
    uint4 r;
    r.x = (u32)o[0] | ((u32)o[1] << 16);
    r.y = (u32)o[2] | ((u32)o[3] << 16);
    r.z = (u32)o[4] | ((u32)o[5] << 16);
    r.w = (u32)o[6] | ((u32)o[7] << 16);
    *(uint4*)(zp + (size_t)node * 128 + fc * 8) = r;
  }
}

// ================= conv GEMM: A in registers (plain loads), B in LDS =================
// 1D grid 782: xb=bid>>1 (128-row stripe), yb=bid&1 (64-col stripe). 4 waves x 32 rows.
template <int DO_STATS>
__global__ __launch_bounds__(256) void k_gemm_reg(
    const u16* __restrict__ A1, const u16* __restrict__ A2,
    const u16* __restrict__ Bp, const float* __restrict__ bias,
    u16* __restrict__ C, int M, float* __restrict__ ssum_out) {
  __shared__ __align__(16) u16 Bs[8][2048];   // 8 panels x (64 rows x 32) = 32KB
  __shared__ float bnbuf[128];
  int t = threadIdx.x;
  int lane = t & 63;
  int w = t >> 6;
  int xb = blockIdx.x >> 1;
  int yb = blockIdx.x & 1;
  int m0 = xb * 128;
  int n0 = yb * 64;
  int fc = lane & 15;
  int c16 = lane >> 4;

  if (DO_STATS && t < 128) bnbuf[t] = 0.f;

  // B staging (L2-hot, fire-and-forget)
  #pragma unroll
  for (int j = 0; j < 8; ++j) {
    int s = (w * 8 + j) * 64 + lane;      // 0..2047
    int p = s >> 8;
    int sp = s & 255;
    int row = sp >> 2;
    int cc = (sp & 3) ^ ((row >> 1) & 3);
    const u16* src = Bp + (size_t)(n0 + row) * 256 + p * 32 + cc * 8;
    GLOAD_LDS16(src, &((u16*)Bs)[s * 8]);
  }

  // A fragments straight to registers: 16 independent coalesced dwordx4 per lane
  bf16x8 af[8][2];
  int wrb = m0 + w * 32;
  #pragma unroll
  for (int mf = 0; mf < 2; ++mf) {
    int rg = wrb + mf * 16 + fc;
    rg = rg < M ? rg : M - 1;
    const u16* a1r = A1 + (size_t)rg * 128 + c16 * 8;
    const u16* a2r = A2 + (size_t)rg * 128 + c16 * 8;
    #pragma unroll
    for (int kt = 0; kt < 4; ++kt) af[kt][mf] = *(const bf16x8*)(a1r + kt * 32);
    #pragma unroll
    for (int kt = 0; kt < 4; ++kt) af[4 + kt][mf] = *(const bf16x8*)(a2r + kt * 32);
  }
  __syncthreads();   // Bs ready (A loads drain at first use)

  // barrier-free K-loop
  f32x4 acc[2][4] = {};
  #pragma unroll
  for (int kt = 0; kt < 8; ++kt) {
    bf16x8 bfr[4];
    #pragma unroll
    for (int nf = 0; nf < 4; ++nf) {
      int row = nf * 16 + fc;
      int cs = c16 ^ ((row >> 1) & 3);
      bfr[nf] = *(const bf16x8*)&Bs[kt][row * 32 + cs * 8];
    }
    #pragma unroll
    for (int mf = 0; mf < 2; ++mf)
      #pragma unroll
      for (int nf = 0; nf < 4; ++nf)
        acc[mf][nf] = __builtin_amdgcn_mfma_f32_16x16x32_bf16(af[kt][mf], bfr[nf], acc[mf][nf], 0, 0, 0);
  }

  // epilogue: bias + stats + direct stores
  float breg[4];
  #pragma unroll
  for (int nf = 0; nf < 4; ++nf) breg[nf] = bias[n0 + nf * 16 + fc];
  float cs_[4] = {}, cq_[4] = {};
  #pragma unroll
  for (int mf = 0; mf < 2; ++mf) {
    #pragma unroll
    for (int j = 0; j < 4; ++j) {
      int rg = wrb + mf * 16 + c16 * 4 + j;
      if (rg < M) {
        #pragma unroll
        for (int nf = 0; nf < 4; ++nf) {
          float v = acc[mf][nf][j] + breg[nf];
          C[(size_t)rg * 128 + n0 + nf * 16 + fc] = f2bf(v);
          if (DO_STATS) { cs_[nf] += v; cq_[nf] = fmaf(v, v, cq_[nf]); }
        }
      }
    }
  }

  if (DO_STATS) {
    #pragma unroll
    for (int nf = 0; nf < 4; ++nf) {
      float s = cs_[nf], q = cq_[nf];
      s += __shfl_xor(s, 16, 64); s += __shfl_xor(s, 32, 64);
      q += __shfl_xor(q, 16, 64); q += __shfl_xor(q, 32, 64);
      if (c16 == 0) {
        atomicAdd(&bnbuf[nf * 16 + fc], s);
        atomicAdd(&bnbuf[64 + nf * 16 + fc], q);
      }
    }
    __syncthreads();
    if (t < 128) {
      int idx = (t < 64) ? (n0 + t) : (128 + n0 + (t - 64));
      atomicAdd(&ssum_out[idx], bnbuf[t]);
    }
  }
}

// ================= fused encoder: x-MLP -> LDS A-tile -> GEMM (B dbuf) =================
// grid (1563, 2): BM=32, BN=64.
__global__ __launch_bounds__(256) void k_enc(
    const float* __restrict__ x, const float* __restrict__ W1,
    const float* __restrict__ b1, const u16* __restrict__ Bp,
    const float* __restrict__ bias, u16* __restrict__ C, int M) {
  __shared__ __align__(16) u16 As[8][1024];   // 8 panels x (32 rows x 32) = 16KB
  __shared__ __align__(16) u16 Bs[2][2048];   // dbuf panels (64 rows x 32) = 8KB
  __shared__ float xs[224];
  int t = threadIdx.x;
  int lane = t & 63;
  int w = t >> 6;
  int m0 = blockIdx.x * 32;
  int n0c = blockIdx.y * 64;
  int fc = lane & 15;
  int c16 = lane >> 4;

  auto stageB = [&](int kt, int b) {
    int s = t;                             // 256 slots
    int row = s >> 2;
    int cc = (s & 3) ^ ((row >> 1) & 3);
    const u16* src = Bp + (size_t)(n0c + row) * 256 + kt * 32 + cc * 8;
    GLOAD_LDS16(src, &Bs[b][s * 8]);
  };

  stageB(0, 0);
  for (int i = t; i < 224; i += 256) {
    int gi = m0 * 7 + i;
    xs[i] = (gi < M * 7) ? x[gi] : 0.f;
  }
  float w1r[7];
  #pragma unroll
  for (int k = 0; k < 7; ++k) w1r[k] = W1[t * 7 + k];
  float b1r = b1[t];
  __syncthreads();

  // h[r][t] -> A-tile swizzled
  int p = t >> 5;
  int cq = (t & 31) >> 3;
  int e8 = t & 7;
  for (int r = 0; r < 32; ++r) {
    float acc = b1r;
    #pragma unroll
    for (int k = 0; k < 7; ++k) acc = fmaf(w1r[k], xs[r * 7 + k], acc);
    As[p][r * 32 + (cq ^ ((r >> 1) & 3)) * 8 + e8] = f2bf(fmaxf(acc, 0.f));
  }
  __syncthreads();

  f32x4 acc[2] = {};
  #pragma unroll
  for (int kt = 0; kt < 8; ++kt) {
    const int b = kt & 1;
    if (kt + 1 < 8) stageB(kt + 1, b ^ 1);
    bf16x8 afr[2], bf;
    #pragma unroll
    for (int mf = 0; mf < 2; ++mf) {
      int row = mf * 16 + fc;
      int cs = c16 ^ ((row >> 1) & 3);
      afr[mf] = *(const bf16x8*)&As[kt][row * 32 + cs * 8];
    }
    {
      int row = w * 16 + fc;
      int cs = c16 ^ ((row >> 1) & 3);
      bf = *(const bf16x8*)&Bs[b][row * 32 + cs * 8];
    }
    #pragma unroll
    for (int mf = 0; mf < 2; ++mf)
      acc[mf] = __builtin_amdgcn_mfma_f32_16x16x32_bf16(afr[mf], bf, acc[mf], 0, 0, 0);
    __syncthreads();
  }

  float breg = bias[n0c + w * 16 + fc];
  #pragma unroll
  for (int mf = 0; mf < 2; ++mf)
    #pragma unroll
    for (int j = 0; j < 4; ++j) {
      int rg = m0 + mf * 16 + c16 * 4 + j;
      if (rg < M) C[(size_t)rg * 128 + n0c + w * 16 + fc] = f2bf(acc[mf][j] + breg);
    }
}

// ================= decoder: A=z5 in regs, full N=256 in-block, direct store =================
// grid 1563: BM=32. Wave w covers hidden cols w*64..+63. No global atomics.
__global__ __launch_bounds__(256) void k_dec(
    const u16* __restrict__ z5, const u16* __restrict__ Bpd,
    const float* __restrict__ b1, const float* __restrict__ W2,
    const float* __restrict__ b2, float* __restrict__ out, int M) {
  __shared__ __align__(16) u16 Bs[4][8192];   // 4 panels x (256 rows x 32) = 64KB
  __shared__ float obuf[128];                  // [32 rows][4 o]
  int t = threadIdx.x;
  int lane = t & 63;
  int w = t >> 6;
  int m0 = blockIdx.x * 32;
  int fc = lane & 15;
  int c16 = lane >> 4;

  if (t < 128) obuf[t] = 0.f;

  // B staging: 4096 slots, 16/thread
  #pragma unroll
  for (int j = 0; j < 16; ++j) {
    int s = (w * 16 + j) * 64 + lane;
    int p = s >> 10;
    int sp = s & 1023;
    int row = sp >> 2;
    int cc = (sp & 3) ^ ((row >> 1) & 3);
    const u16* src = Bpd + (size_t)row * 128 + p * 32 + cc * 8;
    GLOAD_LDS16(src, &((u16*)Bs)[s * 8]);
  }

  // A fragments to registers (all waves same 32 rows, L1-absorbed)
  bf16x8 af[4][2];
  #pragma unroll
  for (int mf = 0; mf < 2; ++mf) {
    int rg = m0 + mf * 16 + fc;
    rg = rg < M ? rg : M - 1;
    const u16* ar = z5 + (size_t)rg * 128 + c16 * 8;
    #pragma unroll
    for (int kt = 0; kt < 4; ++kt) af[kt][mf] = *(const bf16x8*)(ar + kt * 32);
  }
  __syncthreads();

  f32x4 acc[2][4] = {};
  #pragma unroll
  for (int kt = 0; kt < 4; ++kt) {
    bf16x8 bfr[4];
    #pragma unroll
    for (int nf = 0; nf < 4; ++nf) {
      int row = w * 64 + nf * 16 + fc;
      int cs = c16 ^ ((row >> 1) & 3);
      bfr[nf] = *(const bf16x8*)&Bs[kt][row * 32 + cs * 8];
    }
    #pragma unroll
    for (int mf = 0; mf < 2; ++mf)
      #pragma unroll
      for (int nf = 0; nf < 4; ++nf)
        acc[mf][nf] = __builtin_amdgcn_mfma_f32_16x16x32_bf16(af[kt][mf], bfr[nf], acc[mf][nf], 0, 0, 0);
  }

  float b1r[4], w2r[4][4];
  #pragma unroll
  for (int nf = 0; nf < 4; ++nf) {
    int col = w * 64 + nf * 16 + fc;
    b1r[nf] = b1[col];
    #pragma unroll
    for (int o = 0; o < 4; ++o) w2r[o][nf] = W2[o * 256 + col];
  }
  float po[2][4][4] = {};
  #pragma unroll
  for (int mf = 0; mf < 2; ++mf)
    #pragma unroll
    for (int j = 0; j < 4; ++j)
      #pragma unroll
      for (int nf = 0; nf < 4; ++nf) {
        float hv = fmaxf(acc[mf][nf][j] + b1r[nf], 0.f);
        #pragma unroll
        for (int o = 0; o < 4; ++o) po[mf][j][o] = fmaf(hv, w2r[o][nf], po[mf][j][o]);
      }
  #pragma unroll
  for (int mf = 0; mf < 2; ++mf)
    #pragma unroll
    for (int j = 0; j < 4; ++j)
      #pragma unroll
      for (int o = 0; o < 4; ++o) {
        float v = po[mf][j][o];
        v += __shfl_xor(v, 1, 16);
        v += __shfl_xor(v, 2, 16);
        v += __shfl_xor(v, 4, 16);
        po[mf][j][o] = v + __shfl_xor(v, 8, 16);
      }
  if (fc == 0) {
    #pragma unroll
    for (int mf = 0; mf < 2; ++mf)
      #pragma unroll
      for (int j = 0; j < 4; ++j) {
        int rl = mf * 16 + c16 * 4 + j;
        #pragma unroll
        for (int o = 0; o < 4; ++o) atomicAdd(&obuf[rl * 4 + o], po[mf][j][o]);
      }
  }
  __syncthreads();
  if (t < 128) {
    int row = t >> 2;
    int rg = m0 + row;
    if (rg < M) out[(size_t)rg * 4 + (t & 3)] = obuf[t] + b2[t & 3];
  }
}

// ---------------- launch ----------------
extern "C" void kernel_launch(void* const* d_in, const int* in_sizes, int n_in,
                              void* d_out, int out_size, void* d_ws, size_t ws_size,
                              hipStream_t stream) {
  const float* x     = (const float*)d_in[0];
  const int*   ei    = (const int*)d_in[1];
  const float* encW1 = (const float*)d_in[2];
  const float* encb1 = (const float*)d_in[3];
  const float* encW2 = (const float*)d_in[4];
  const float* encb2 = (const float*)d_in[5];
  const float* Wl    = (const float*)d_in[6];
  const float* bl    = (const float*)d_in[7];
  const float* Wr    = (const float*)d_in[8];
  const float* gamma = (const float*)d_in[9];
  const float* beta  = (const float*)d_in[10];
  const float* decW1 = (const float*)d_in[11];
  const float* decb1 = (const float*)d_in[12];
  const float* decW2 = (const float*)d_in[13];
  const float* decb2 = (const float*)d_in[14];
  float* out = (float*)d_out;

  const int M = M_NODES, E = E_EDGES;
  char* p = (char*)d_ws;
  auto take = [&](size_t b) { char* r = p; p += (b + 255) & ~(size_t)255; return r; };
  u16* zA     = (u16*)take((size_t)M * 128 * 2);
  u16* zB     = (u16*)take((size_t)M * 128 * 2);
  u16* zP     = (u16*)take((size_t)M * 128 * 2);
  u16* mean   = (u16*)take((size_t)M * 128 * 2);
  u16* Bpack  = (u16*)take((size_t)229376 * 2);
  int* cnt    = (int*)take((size_t)M * 4);
  int* bucket = (int*)take((size_t)M * BKT * 4);
  float* ssums = (float*)take(4 * 256 * 4);

  const int* srcp = ei;
  const int* dstp = ei + E;

  k_prep<<<896, 256, 0, stream>>>(encW2, Wl, Wr, decW1, Bpack);
  hipMemsetAsync(cnt, 0, (size_t)M * 4, stream);
  hipMemsetAsync(ssums, 0, 4 * 256 * 4, stream);
  k_place<<<(E + 255) / 256, 256, 0, stream>>>(srcp, dstp, cnt, bucket, E);

  const int GX32 = (M + 31) / 32;    // 1563
  const int GX128 = (M + 127) / 128; // 391

  k_enc<<<dim3(GX32, 2), 256, 0, stream>>>(x, encW1, encb1, Bpack, encb2, zA, M);

  u16* cur = zA;
  u16* nxt = zB;
  for (int i = 0; i < 5; ++i) {
    if (i == 0) {
      k_agg<0><<<M / 4, 256, 0, stream>>>(cur, cnt, bucket, nullptr, nullptr, nullptr,
                                          mean, zP, M);
    } else {
      k_agg<1><<<M / 4, 256, 0, stream>>>(cur, cnt, bucket, ssums + (i - 1) * 256,
                                          gamma + (size_t)(i - 1) * 128,
                                          beta + (size_t)(i - 1) * 128, mean, zP, M);
    }
    const u16* A2 = (i == 0) ? cur : zP;
    if (i < 4) {
      k_gemm_reg<1><<<GX128 * 2, 256, 0, stream>>>(mean, A2, Bpack + 32768 + i * 32768,
                                                   bl + (size_t)i * 128, nxt, M,
                                                   ssums + i * 256);
    } else {
      k_gemm_reg<0><<<GX128 * 2, 256, 0, stream>>>(mean, A2, Bpack + 32768 + i * 32768,
                                                   bl + (size_t)i * 128, nxt, M, nullptr);
    }
    u16* tswap = cur; cur = nxt; nxt = tswap;
  }

  k_dec<<<GX32, 256, 0, stream>>>(cur, Bpack + 196608, decb1, decW2, decb2, out, M);
}

// Round 11
// 380.898 us; speedup vs baseline: 1.7495x; 1.0001x over previous
//
#include <hip/hip_runtime.h>

using u16 = unsigned short;
using u32 = unsigned int;

#define M_NODES 50000
#define E_EDGES 600000
#define EPS_BN 1e-5f
#define BKT 48

typedef __attribute__((ext_vector_type(8))) short bf16x8;
typedef __attribute__((ext_vector_type(4))) float f32x4;

__device__ __forceinline__ float bf2f(u16 v) {
  union { u32 u; float f; } x; x.u = ((u32)v) << 16; return x.f;
}
__device__ __forceinline__ float lo16f(u32 v) {
  union { u32 u; float f; } x; x.u = v << 16; return x.f;
}
__device__ __forceinline__ float hi16f(u32 v) {
  union { u32 u; float f; } x; x.u = v & 0xffff0000u; return x.f;
}
__device__ __forceinline__ u16 f2bf(float f) {
  union { float f; u32 u; } x; x.f = f;
  u32 r = x.u + 0x7fffu + ((x.u >> 16) & 1u);
  return (u16)(r >> 16);
}

// ---------------- bucket build ----------------
__global__ void k_place(const int* __restrict__ src, const int* __restrict__ dst,
                        int* __restrict__ cnt, int* __restrict__ bucket, int n) {
  int e = blockIdx.x * blockDim.x + threadIdx.x;
  if (e < n) {
    int d = dst[e];
    int p = atomicAdd(&cnt[d], 1);
    if (p < BKT) bucket[d * BKT + p] = src[e];
  }
}

// ---------------- weight prep ----------------
// [0,32768) encW2 [128][256]; [32768+i*32768) conv i [128][256]=[Wl|Wr]; [196608,229376) decW1 [256][128]
__global__ __launch_bounds__(256) void k_prep(const float* __restrict__ encW2,
                                              const float* __restrict__ Wl,
                                              const float* __restrict__ Wr,
                                              const float* __restrict__ decW1,
                                              u16* __restrict__ Bp) {
  int e = blockIdx.x * 256 + threadIdx.x;
  float v;
  if (e < 32768) {
    v = encW2[e];
  } else if (e < 196608) {
    int r = e - 32768;
    int i = r >> 15;
    int rr = r & 32767;
    int n = rr >> 8;
    int k = rr & 255;
    v = (k < 128) ? Wl[i * 16384 + n * 128 + k] : Wr[i * 16384 + n * 128 + (k - 128)];
  } else {
    v = decW1[e - 196608];
  }
  Bp[e] = f2bf(v);
}

// ---------------- fused mean-aggregation (+BN+relu of previous layer) ----------------
template <int TRANS>
__global__ __launch_bounds__(256) void k_agg(const u16* __restrict__ z,
                                             const int* __restrict__ cnt,
                                             const int* __restrict__ bucket,
                                             const float* __restrict__ ssum,
                                             const float* __restrict__ gamma,
                                             const float* __restrict__ beta,
                                             u16* __restrict__ mean,
                                             u16* __restrict__ zp, int M) {
  __shared__ float s_sc[256];
  int t = threadIdx.x;
  if (TRANS) {
    if (t < 128) {
      float m = ssum[t] * (1.0f / M_NODES);
      float var = ssum[128 + t] * (1.0f / M_NODES) - m * m;
      float s = gamma[t] * rsqrtf(var + EPS_BN);
      s_sc[t] = s;
      s_sc[128 + t] = beta[t] - m * s;
    }
    __syncthreads();
  }
  int node = blockIdx.x * 4 + (t >> 6);
  int lane = t & 63;
  int slot = lane >> 4;
  int fc = lane & 15;
  float sreg[8], treg[8];
  if (TRANS) {
    #pragma unroll
    for (int i = 0; i < 8; ++i) { sreg[i] = s_sc[fc * 8 + i]; treg[i] = s_sc[128 + fc * 8 + i]; }
  }
  int deg = cnt[node];
  int nd = deg < BKT ? deg : BKT;
  const int* bk = bucket + (size_t)node * BKT;
  float a[8] = {};
  for (int j = slot; j < nd; j += 4) {
    int s = bk[j];
    uint4 v = *(const uint4*)(z + (size_t)s * 128 + fc * 8);
    float f[8] = {lo16f(v.x), hi16f(v.x), lo16f(v.y), hi16f(v.y),
                  lo16f(v.z), hi16f(v.z), lo16f(v.w), hi16f(v.w)};
    #pragma unroll
    for (int i = 0; i < 8; ++i) {
      float vv = TRANS ? fmaxf(fmaf(f[i], sreg[i], treg[i]), 0.f) : f[i];
      a[i] += vv;
    }
  }
  #pragma unroll
  for (int i = 0; i < 8; ++i) {
    a[i] += __shfl_xor(a[i], 16, 64);
    a[i] += __shfl_xor(a[i], 32, 64);
  }
  if (slot == 0) {
    float inv = 1.0f / (float)(deg > 1 ? deg : 1);
    uint4 r;
    r.x = (u32)f2bf(a[0] * inv) | ((u32)f2bf(a[1] * inv) << 16);
    r.y = (u32)f2bf(a[2] * inv) | ((u32)f2bf(a[3] * inv) << 16);
    r.z = (u32)f2bf(a[4] * inv) | ((u32)f2bf(a[5] * inv) << 16);
    r.w = (u32)f2bf(a[6] * inv) | ((u32)f2bf(a[7] * inv) << 16);
    *(uint4*)(mean + (size_t)node * 128 + fc * 8) = r;
  }
  if (TRANS && slot == 1) {
    uint4 v = *(const uint4*)(z + (size_t)node * 128 + fc * 8);
    float f[8] = {lo16f(v.x), hi16f(v.x), lo16f(v.y), hi16f(v.y),
                  lo16f(v.z), hi16f(v.z), lo16f(v.w), hi16f(v.w)};
    u16 o[8];
    #pragma unroll
    for (int i = 0; i < 8; ++i) o[i] = f2bf(fmaxf(fmaf(f[i], sreg[i], treg[i]), 0.f));
    uint4 r;
    r.x = (u32)o[0] | ((u32)o[1] << 16);
    r.y = (u32)o[2] | ((u32)o[3] << 16);
    r.z = (u32)o[4] | ((u32)o[5] << 16);
    r.w = (u32)o[6] | ((u32)o[7] << 16);
    *(uint4*)(zp + (size_t)node * 128 + fc * 8) = r;
  }
}

// ================= conv GEMM: A in regs, B reg->LDS, C restaged in LDS =================
// 1D grid 782: xb=bid>>1 (128-row stripe), yb=bid&1 (64-col stripe). 4 waves x 32 rows.
template <int DO_STATS>
__global__ __launch_bounds__(256) void k_gemm_reg(
    const u16* __restrict__ A1, const u16* __restrict__ A2,
    const u16* __restrict__ Bp, const float* __restrict__ bias,
    u16* __restrict__ C, int M, float* __restrict__ ssum_out) {
  __shared__ __align__(16) u16 Bs[8][2048];   // 32KB; reused as C-stage [128][64]
  __shared__ float bnbuf[128];
  int t = threadIdx.x;
  int lane = t & 63;
  int w = t >> 6;
  int xb = blockIdx.x >> 1;
  int yb = blockIdx.x & 1;
  int m0 = xb * 128;
  int n0 = yb * 64;
  int fc = lane & 15;
  int c16 = lane >> 4;

  if (DO_STATS && t < 128) bnbuf[t] = 0.f;

  // ---- B: plain uint4 loads to regs (all independent, issued first) ----
  uint4 bst[8];
  #pragma unroll
  for (int j = 0; j < 8; ++j) {
    int s = j * 256 + t;                  // 0..2047 16B slots
    int p = s >> 8;
    int sp = s & 255;
    int row = sp >> 2;
    int cc = (sp & 3) ^ ((row >> 1) & 3);
    bst[j] = *(const uint4*)(Bp + (size_t)(n0 + row) * 256 + p * 32 + cc * 8);
  }

  // ---- A fragments straight to registers: 16 independent dwordx4 per lane ----
  bf16x8 af[8][2];
  int wrb = m0 + w * 32;
  #pragma unroll
  for (int mf = 0; mf < 2; ++mf) {
    int rg = wrb + mf * 16 + fc;
    rg = rg < M ? rg : M - 1;
    const u16* a1r = A1 + (size_t)rg * 128 + c16 * 8;
    const u16* a2r = A2 + (size_t)rg * 128 + c16 * 8;
    #pragma unroll
    for (int kt = 0; kt < 4; ++kt) af[kt][mf] = *(const bf16x8*)(a1r + kt * 32);
    #pragma unroll
    for (int kt = 0; kt < 4; ++kt) af[4 + kt][mf] = *(const bf16x8*)(a2r + kt * 32);
  }

  // ---- write B to LDS ----
  #pragma unroll
  for (int j = 0; j < 8; ++j) {
    int s = j * 256 + t;
    *(uint4*)&((u16*)Bs)[s * 8] = bst[j];
  }
  __syncthreads();

  // ---- barrier-free K-loop ----
  f32x4 acc[2][4] = {};
  #pragma unroll
  for (int kt = 0; kt < 8; ++kt) {
    bf16x8 bfr[4];
    #pragma unroll
    for (int nf = 0; nf < 4; ++nf) {
      int row = nf * 16 + fc;
      int cs = c16 ^ ((row >> 1) & 3);
      bfr[nf] = *(const bf16x8*)&Bs[kt][row * 32 + cs * 8];
    }
    #pragma unroll
    for (int mf = 0; mf < 2; ++mf)
      #pragma unroll
      for (int nf = 0; nf < 4; ++nf)
        acc[mf][nf] = __builtin_amdgcn_mfma_f32_16x16x32_bf16(af[kt][mf], bfr[nf], acc[mf][nf], 0, 0, 0);
  }

  // ---- epilogue: bias + stats; C through LDS (reuse Bs) for full-line stores ----
  float breg[4];
  #pragma unroll
  for (int nf = 0; nf < 4; ++nf) breg[nf] = bias[n0 + nf * 16 + fc];

  __syncthreads();   // all waves done reading Bs
  u16* Cl = (u16*)Bs;  // [128][64]
  float cs_[4] = {}, cq_[4] = {};
  #pragma unroll
  for (int mf = 0; mf < 2; ++mf) {
    #pragma unroll
    for (int j = 0; j < 4; ++j) {
      int rl = w * 32 + mf * 16 + c16 * 4 + j;
      bool valid = (m0 + rl) < M;
      #pragma unroll
      for (int nf = 0; nf < 4; ++nf) {
        float v = acc[mf][nf][j] + breg[nf];
        Cl[rl * 64 + nf * 16 + fc] = f2bf(v);
        if (DO_STATS && valid) { cs_[nf] += v; cq_[nf] = fmaf(v, v, cq_[nf]); }
      }
    }
  }
  __syncthreads();
  #pragma unroll
  for (int j2 = 0; j2 < 4; ++j2) {
    int ci = j2 * 256 + t;               // 0..1023 chunks
    int row = ci >> 3;
    int cx = ci & 7;
    int rg = m0 + row;
    if (rg < M)
      *(uint4*)(C + (size_t)rg * 128 + n0 + cx * 8) = *(const uint4*)&Cl[row * 64 + cx * 8];
  }

  if (DO_STATS) {
    #pragma unroll
    for (int nf = 0; nf < 4; ++nf) {
      float s = cs_[nf], q = cq_[nf];
      s += __shfl_xor(s, 16, 64); s += __shfl_xor(s, 32, 64);
      q += __shfl_xor(q, 16, 64); q += __shfl_xor(q, 32, 64);
      if (c16 == 0) {
        atomicAdd(&bnbuf[nf * 16 + fc], s);
        atomicAdd(&bnbuf[64 + nf * 16 + fc], q);
      }
    }
    __syncthreads();
    if (t < 128) {
      int idx = (t < 64) ? (n0 + t) : (128 + n0 + (t - 64));
      atomicAdd(&ssum_out[idx], bnbuf[t]);
    }
  }
}

// ================= fused encoder: x-MLP -> LDS A-tile -> all-resident GEMM =================
// grid (1563, 2): BM=32, BN=64.
__global__ __launch_bounds__(256) void k_enc(
    const float* __restrict__ x, const float* __restrict__ W1,
    const float* __restrict__ b1, const u16* __restrict__ Bp,
    const float* __restrict__ bias, u16* __restrict__ C, int M) {
  __shared__ __align__(16) u16 As[8][1024];   // 16KB; reused as C-stage [32][64]
  __shared__ __align__(16) u16 Bs[8][2048];   // 32KB
  __shared__ float xs[224];
  int t = threadIdx.x;
  int lane = t & 63;
  int w = t >> 6;
  int m0 = blockIdx.x * 32;
  int n0c = blockIdx.y * 64;
  int fc = lane & 15;
  int c16 = lane >> 4;

  // B loads first (land during MLP compute)
  uint4 bst[8];
  #pragma unroll
  for (int j = 0; j < 8; ++j) {
    int s = j * 256 + t;
    int p = s >> 8;
    int sp = s & 255;
    int row = sp >> 2;
    int cc = (sp & 3) ^ ((row >> 1) & 3);
    bst[j] = *(const uint4*)(Bp + (size_t)(n0c + row) * 256 + p * 32 + cc * 8);
  }
  for (int i = t; i < 224; i += 256) {
    int gi = m0 * 7 + i;
    xs[i] = (gi < M * 7) ? x[gi] : 0.f;
  }
  float w1r[7];
  #pragma unroll
  for (int k = 0; k < 7; ++k) w1r[k] = W1[t * 7 + k];
  float b1r = b1[t];
  __syncthreads();

  // h[r][t] -> A-tile swizzled
  int p = t >> 5;
  int cq = (t & 31) >> 3;
  int e8 = t & 7;
  for (int r = 0; r < 32; ++r) {
    float acc = b1r;
    #pragma unroll
    for (int k = 0; k < 7; ++k) acc = fmaf(w1r[k], xs[r * 7 + k], acc);
    As[p][r * 32 + (cq ^ ((r >> 1) & 3)) * 8 + e8] = f2bf(fmaxf(acc, 0.f));
  }
  // write B to LDS
  #pragma unroll
  for (int j = 0; j < 8; ++j) {
    int s = j * 256 + t;
    *(uint4*)&((u16*)Bs)[s * 8] = bst[j];
  }
  __syncthreads();

  f32x4 acc[2] = {};
  #pragma unroll
  for (int kt = 0; kt < 8; ++kt) {
    bf16x8 afr[2], bf;
    #pragma unroll
    for (int mf = 0; mf < 2; ++mf) {
      int row = mf * 16 + fc;
      int cs = c16 ^ ((row >> 1) & 3);
      afr[mf] = *(const bf16x8*)&As[kt][row * 32 + cs * 8];
    }
    {
      int row = w * 16 + fc;
      int cs = c16 ^ ((row >> 1) & 3);
      bf = *(const bf16x8*)&Bs[kt][row * 32 + cs * 8];
    }
    #pragma unroll
    for (int mf = 0; mf < 2; ++mf)
      acc[mf] = __builtin_amdgcn_mfma_f32_16x16x32_bf16(afr[mf], bf, acc[mf], 0, 0, 0);
  }

  float breg = bias[n0c + w * 16 + fc];
  __syncthreads();   // done reading As
  u16* Cl = (u16*)As;  // [32][64]
  #pragma unroll
  for (int mf = 0; mf < 2; ++mf)
    #pragma unroll
    for (int j = 0; j < 4; ++j) {
      int rl = mf * 16 + c16 * 4 + j;
      Cl[rl * 64 + w * 16 + fc] = f2bf(acc[mf][j] + breg);
    }
  __syncthreads();
  {
    int row = t >> 3;                     // 0..31
    int cx = t & 7;
    int rg = m0 + row;
    if (rg < M)
      *(uint4*)(C + (size_t)rg * 128 + n0c + cx * 8) = *(const uint4*)&Cl[row * 64 + cx * 8];
  }
}

// ================= decoder: A=z5 in regs, B reg->LDS (64KB), direct store =================
__global__ __launch_bounds__(256) void k_dec(
    const u16* __restrict__ z5, const u16* __restrict__ Bpd,
    const float* __restrict__ b1, const float* __restrict__ W2,
    const float* __restrict__ b2, float* __restrict__ out, int M) {
  __shared__ __align__(16) u16 Bs[4][8192];   // 64KB
  __shared__ float obuf[128];
  int t = threadIdx.x;
  int lane = t & 63;
  int w = t >> 6;
  int m0 = blockIdx.x * 32;
  int fc = lane & 15;
  int c16 = lane >> 4;

  if (t < 128) obuf[t] = 0.f;

  // A fragments to registers
  bf16x8 af[4][2];
  #pragma unroll
  for (int mf = 0; mf < 2; ++mf) {
    int rg = m0 + mf * 16 + fc;
    rg = rg < M ? rg : M - 1;
    const u16* ar = z5 + (size_t)rg * 128 + c16 * 8;
    #pragma unroll
    for (int kt = 0; kt < 4; ++kt) af[kt][mf] = *(const bf16x8*)(ar + kt * 32);
  }

  // B: 4096 slots in 2 reg-staged rounds
  #pragma unroll
  for (int r = 0; r < 2; ++r) {
    uint4 bst[8];
    #pragma unroll
    for (int j = 0; j < 8; ++j) {
      int s = r * 2048 + j * 256 + t;
      int p = s >> 10;
      int sp = s & 1023;
      int row = sp >> 2;
      int cc = (sp & 3) ^ ((row >> 1) & 3);
      bst[j] = *(const uint4*)(Bpd + (size_t)row * 128 + p * 32 + cc * 8);
    }
    #pragma unroll
    for (int j = 0; j < 8; ++j) {
      int s = r * 2048 + j * 256 + t;
      *(uint4*)&((u16*)Bs)[s * 8] = bst[j];
    }
  }
  __syncthreads();

  f32x4 acc[2][4] = {};
  #pragma unroll
  for (int kt = 0; kt < 4; ++kt) {
    bf16x8 bfr[4];
    #pragma unroll
    for (int nf = 0; nf < 4; ++nf) {
      int row = w * 64 + nf * 16 + fc;
      int cs = c16 ^ ((row >> 1) & 3);
      bfr[nf] = *(const bf16x8*)&Bs[kt][row * 32 + cs * 8];
    }
    #pragma unroll
    for (int mf = 0; mf < 2; ++mf)
      #pragma unroll
      for (int nf = 0; nf < 4; ++nf)
        acc[mf][nf] = __builtin_amdgcn_mfma_f32_16x16x32_bf16(af[kt][mf], bfr[nf], acc[mf][nf], 0, 0, 0);
  }

  float b1r[4], w2r[4][4];
  #pragma unroll
  for (int nf = 0; nf < 4; ++nf) {
    int col = w * 64 + nf * 16 + fc;
    b1r[nf] = b1[col];
    #pragma unroll
    for (int o = 0; o < 4; ++o) w2r[o][nf] = W2[o * 256 + col];
  }
  float po[2][4][4] = {};
  #pragma unroll
  for (int mf = 0; mf < 2; ++mf)
    #pragma unroll
    for (int j = 0; j < 4; ++j)
      #pragma unroll
      for (int nf = 0; nf < 4; ++nf) {
        float hv = fmaxf(acc[mf][nf][j] + b1r[nf], 0.f);
        #pragma unroll
        for (int o = 0; o < 4; ++o) po[mf][j][o] = fmaf(hv, w2r[o][nf], po[mf][j][o]);
      }
  #pragma unroll
  for (int mf = 0; mf < 2; ++mf)
    #pragma unroll
    for (int j = 0; j < 4; ++j)
      #pragma unroll
      for (int o = 0; o < 4; ++o) {
        float v = po[mf][j][o];
        v += __shfl_xor(v, 1, 16);
        v += __shfl_xor(v, 2, 16);
        v += __shfl_xor(v, 4, 16);
        po[mf][j][o] = v + __shfl_xor(v, 8, 16);
      }
  if (fc == 0) {
    #pragma unroll
    for (int mf = 0; mf < 2; ++mf)
      #pragma unroll
      for (int j = 0; j < 4; ++j) {
        int rl = mf * 16 + c16 * 4 + j;
        #pragma unroll
        for (int o = 0; o < 4; ++o) atomicAdd(&obuf[rl * 4 + o], po[mf][j][o]);
      }
  }
  __syncthreads();
  if (t < 128) {
    int row = t >> 2;
    int rg = m0 + row;
    if (rg < M) out[(size_t)rg * 4 + (t & 3)] = obuf[t] + b2[t & 3];
  }
}

// ---------------- launch ----------------
extern "C" void kernel_launch(void* const* d_in, const int* in_sizes, int n_in,
                              void* d_out, int out_size, void* d_ws, size_t ws_size,
                              hipStream_t stream) {
  const float* x     = (const float*)d_in[0];
  const int*   ei    = (const int*)d_in[1];
  const float* encW1 = (const float*)d_in[2];
  const float* encb1 = (const float*)d_in[3];
  const float* encW2 = (const float*)d_in[4];
  const float* encb2 = (const float*)d_in[5];
  const float* Wl    = (const float*)d_in[6];
  const float* bl    = (const float*)d_in[7];
  const float* Wr    = (const float*)d_in[8];
  const float* gamma = (const float*)d_in[9];
  const float* beta  = (const float*)d_in[10];
  const float* decW1 = (const float*)d_in[11];
  const float* decb1 = (const float*)d_in[12];
  const float* decW2 = (const float*)d_in[13];
  const float* decb2 = (const float*)d_in[14];
  float* out = (float*)d_out;

  const int M = M_NODES, E = E_EDGES;
  char* p = (char*)d_ws;
  auto take = [&](size_t b) { char* r = p; p += (b + 255) & ~(size_t)255; return r; };
  u16* zA     = (u16*)take((size_t)M * 128 * 2);
  u16* zB     = (u16*)take((size_t)M * 128 * 2);
  u16* zP     = (u16*)take((size_t)M * 128 * 2);
  u16* mean   = (u16*)take((size_t)M * 128 * 2);
  u16* Bpack  = (u16*)take((size_t)229376 * 2);
  int* cnt    = (int*)take((size_t)M * 4);
  int* bucket = (int*)take((size_t)M * BKT * 4);
  float* ssums = (float*)take(4 * 256 * 4);

  const int* srcp = ei;
  const int* dstp = ei + E;

  k_prep<<<896, 256, 0, stream>>>(encW2, Wl, Wr, decW1, Bpack);
  hipMemsetAsync(cnt, 0, (size_t)M * 4, stream);
  hipMemsetAsync(ssums, 0, 4 * 256 * 4, stream);
  k_place<<<(E + 255) / 256, 256, 0, stream>>>(srcp, dstp, cnt, bucket, E);

  const int GX32 = (M + 31) / 32;    // 1563
  const int GX128 = (M + 127) / 128; // 391

  k_enc<<<dim3(GX32, 2), 256, 0, stream>>>(x, encW1, encb1, Bpack, encb2, zA, M);

  u16* cur = zA;
  u16* nxt = zB;
  for (int i = 0; i < 5; ++i) {
    if (i == 0) {
      k_agg<0><<<M / 4, 256, 0, stream>>>(cur, cnt, bucket, nullptr, nullptr, nullptr,
                                          mean, zP, M);
    } else {
      k_agg<1><<<M / 4, 256, 0, stream>>>(cur, cnt, bucket, ssums + (i - 1) * 256,
                                          gamma + (size_t)(i - 1) * 128,
                                          beta + (size_t)(i - 1) * 128, mean, zP, M);
    }
    const u16* A2 = (i == 0) ? cur : zP;
    if (i < 4) {
      k_gemm_reg<1><<<GX128 * 2, 256, 0, stream>>>(mean, A2, Bpack + 32768 + i * 32768,
                                                   bl + (size_t)i * 128, nxt, M,
                                                   ssums + i * 256);
    } else {
      k_gemm_reg<0><<<GX128 * 2, 256, 0, stream>>>(mean, A2, Bpack + 32768 + i * 32768,
                                                   bl + (size_t)i * 128, nxt, M, nullptr);
    }
    u16* tswap = cur; cur = nxt; nxt = tswap;
  }

  k_dec<<<GX32, 256, 0, stream>>>(cur, Bpack + 196608, decb1, decW2, decb2, out, M);
}

// Round 12
// 372.323 us; speedup vs baseline: 1.7898x; 1.0230x over previous
//
#include <hip/hip_runtime.h>

using u16 = unsigned short;
using u32 = unsigned int;

#define M_NODES 50000
#define E_EDGES 600000
#define EPS_BN 1e-5f
#define BKT 48

typedef __attribute__((ext_vector_type(8))) short bf16x8;
typedef __attribute__((ext_vector_type(4))) float f32x4;

__device__ __forceinline__ float bf2f(u16 v) {
  union { u32 u; float f; } x; x.u = ((u32)v) << 16; return x.f;
}
__device__ __forceinline__ float lo16f(u32 v) {
  union { u32 u; float f; } x; x.u = v << 16; return x.f;
}
__device__ __forceinline__ float hi16f(u32 v) {
  union { u32 u; float f; } x; x.u = v & 0xffff0000u; return x.f;
}
__device__ __forceinline__ u16 f2bf(float f) {
  union { float f; u32 u; } x; x.f = f;
  u32 r = x.u + 0x7fffu + ((x.u >> 16) & 1u);
  return (u16)(r >> 16);
}

// ---------------- bucket build ----------------
__global__ void k_place(const int* __restrict__ src, const int* __restrict__ dst,
                        int* __restrict__ cnt, int* __restrict__ bucket, int n) {
  int e = blockIdx.x * blockDim.x + threadIdx.x;
  if (e < n) {
    int d = dst[e];
    int p = atomicAdd(&cnt[d], 1);
    if (p < BKT) bucket[d * BKT + p] = src[e];
  }
}

// ---------------- weight prep ----------------
// [0,32768) encW2 [128][256]; [32768+i*32768) conv i [128][256]=[Wl|Wr]; [196608,229376) decW1 [256][128]
__global__ __launch_bounds__(256) void k_prep(const float* __restrict__ encW2,
                                              const float* __restrict__ Wl,
                                              const float* __restrict__ Wr,
                                              const float* __restrict__ decW1,
                                              u16* __restrict__ Bp) {
  int e = blockIdx.x * 256 + threadIdx.x;
  float v;
  if (e < 32768) {
    v = encW2[e];
  } else if (e < 196608) {
    int r = e - 32768;
    int i = r >> 15;
    int rr = r & 32767;
    int n = rr >> 8;
    int k = rr & 255;
    v = (k < 128) ? Wl[i * 16384 + n * 128 + k] : Wr[i * 16384 + n * 128 + (k - 128)];
  } else {
    v = decW1[e - 196608];
  }
  Bp[e] = f2bf(v);
}

// ---------------- fused mean-aggregation (+BN+relu of previous layer) ----------------
template <int TRANS>
__global__ __launch_bounds__(256) void k_agg(const u16* __restrict__ z,
                                             const int* __restrict__ cnt,
                                             const int* __restrict__ bucket,
                                             const float* __restrict__ ssum,
                                             const float* __restrict__ gamma,
                                             const float* __restrict__ beta,
                                             u16* __restrict__ mean,
                                             u16* __restrict__ zp, int M) {
  __shared__ float s_sc[256];
  int t = threadIdx.x;
  if (TRANS) {
    if (t < 128) {
      float m = ssum[t] * (1.0f / M_NODES);
      float var = ssum[128 + t] * (1.0f / M_NODES) - m * m;
      float s = gamma[t] * rsqrtf(var + EPS_BN);
      s_sc[t] = s;
      s_sc[128 + t] = beta[t] - m * s;
    }
    __syncthreads();
  }
  int node = blockIdx.x * 4 + (t >> 6);
  int lane = t & 63;
  int slot = lane >> 4;
  int fc = lane & 15;
  float sreg[8], treg[8];
  if (TRANS) {
    #pragma unroll
    for (int i = 0; i < 8; ++i) { sreg[i] = s_sc[fc * 8 + i]; treg[i] = s_sc[128 + fc * 8 + i]; }
  }
  int deg = cnt[node];
  int nd = deg < BKT ? deg : BKT;
  const int* bk = bucket + (size_t)node * BKT;
  float a[8] = {};
  for (int j = slot; j < nd; j += 4) {
    int s = bk[j];
    uint4 v = *(const uint4*)(z + (size_t)s * 128 + fc * 8);
    float f[8] = {lo16f(v.x), hi16f(v.x), lo16f(v.y), hi16f(v.y),
                  lo16f(v.z), hi16f(v.z), lo16f(v.w), hi16f(v.w)};
    #pragma unroll
    for (int i = 0; i < 8; ++i) {
      float vv = TRANS ? fmaxf(fmaf(f[i], sreg[i], treg[i]), 0.f) : f[i];
      a[i] += vv;
    }
  }
  #pragma unroll
  for (int i = 0; i < 8; ++i) {
    a[i] += __shfl_xor(a[i], 16, 64);
    a[i] += __shfl_xor(a[i], 32, 64);
  }
  if (slot == 0) {
    float inv = 1.0f / (float)(deg > 1 ? deg : 1);
    uint4 r;
    r.x = (u32)f2bf(a[0] * inv) | ((u32)f2bf(a[1] * inv) << 16);
    r.y = (u32)f2bf(a[2] * inv) | ((u32)f2bf(a[3] * inv) << 16);
    r.z = (u32)f2bf(a[4] * inv) | ((u32)f2bf(a[5] * inv) << 16);
    r.w = (u32)f2bf(a[6] * inv) | ((u32)f2bf(a[7] * inv) << 16);
    *(uint4*)(mean + (size_t)node * 128 + fc * 8) = r;
  }
  if (TRANS && slot == 1) {
    uint4 v = *(const uint4*)(z + (size_t)node * 128 + fc * 8);
    float f[8] = {lo16f(v.x), hi16f(v.x), lo16f(v.y), hi16f(v.y),
                  lo16f(v.z), hi16f(v.z), lo16f(v.w), hi16f(v.w)};
    u16 o[8];
    #pragma unroll
    for (int i = 0; i < 8; ++i) o[i] = f2bf(fmaxf(fmaf(f[i], sreg[i], treg[i]), 0.f));
    uint4 r;
    r.x = (u32)o[0] | ((u32)o[1] << 16);
    r.y = (u32)o[2] | ((u32)o[3] << 16);
    r.z = (u32)o[4] | ((u32)o[5] << 16);
    r.w = (u32)o[6] | ((u32)o[7] << 16);
    *(uint4*)(zp + (size_t)node * 128 + fc * 8) = r;
  }
}

// ================= conv GEMM: A in regs, B reg->LDS, C restaged in LDS =================
// 1D grid 782: xb=bid>>1 (128-row stripe), yb=bid&1 (64-col stripe). 4 waves x 32 rows.
template <int DO_STATS>
__global__ __launch_bounds__(256) void k_gemm_reg(
    const u16* __restrict__ A1, const u16* __restrict__ A2,
    const u16* __restrict__ Bp, const float* __restrict__ bias,
    u16* __restrict__ C, int M, float* __restrict__ ssum_out) {
  __shared__ __align__(16) u16 Bs[8][2048];   // 32KB; reused as C-stage [128][64]
  __shared__ float bnbuf[128];
  int t = threadIdx.x;
  int lane = t & 63;
  int w = t >> 6;
  int xb = blockIdx.x >> 1;
  int yb = blockIdx.x & 1;
  int m0 = xb * 128;
  int n0 = yb * 64;
  int fc = lane & 15;
  int c16 = lane >> 4;

  if (DO_STATS && t < 128) bnbuf[t] = 0.f;

  // ---- B: plain uint4 loads to regs (all independent, issued first) ----
  uint4 bst[8];
  #pragma unroll
  for (int j = 0; j < 8; ++j) {
    int s = j * 256 + t;                  // 0..2047 16B slots
    int p = s >> 8;
    int sp = s & 255;
    int row = sp >> 2;
    int cc = (sp & 3) ^ ((row >> 1) & 3);
    bst[j] = *(const uint4*)(Bp + (size_t)(n0 + row) * 256 + p * 32 + cc * 8);
  }

  // ---- A fragments straight to registers: 16 independent dwordx4 per lane ----
  bf16x8 af[8][2];
  int wrb = m0 + w * 32;
  #pragma unroll
  for (int mf = 0; mf < 2; ++mf) {
    int rg = wrb + mf * 16 + fc;
    rg = rg < M ? rg : M - 1;
    const u16* a1r = A1 + (size_t)rg * 128 + c16 * 8;
    const u16* a2r = A2 + (size_t)rg * 128 + c16 * 8;
    #pragma unroll
    for (int kt = 0; kt < 4; ++kt) af[kt][mf] = *(const bf16x8*)(a1r + kt * 32);
    #pragma unroll
    for (int kt = 0; kt < 4; ++kt) af[4 + kt][mf] = *(const bf16x8*)(a2r + kt * 32);
  }

  // ---- write B to LDS ----
  #pragma unroll
  for (int j = 0; j < 8; ++j) {
    int s = j * 256 + t;
    *(uint4*)&((u16*)Bs)[s * 8] = bst[j];
  }
  __syncthreads();

  // ---- barrier-free K-loop ----
  f32x4 acc[2][4] = {};
  #pragma unroll
  for (int kt = 0; kt < 8; ++kt) {
    bf16x8 bfr[4];
    #pragma unroll
    for (int nf = 0; nf < 4; ++nf) {
      int row = nf * 16 + fc;
      int cs = c16 ^ ((row >> 1) & 3);
      bfr[nf] = *(const bf16x8*)&Bs[kt][row * 32 + cs * 8];
    }
    #pragma unroll
    for (int mf = 0; mf < 2; ++mf)
      #pragma unroll
      for (int nf = 0; nf < 4; ++nf)
        acc[mf][nf] = __builtin_amdgcn_mfma_f32_16x16x32_bf16(af[kt][mf], bfr[nf], acc[mf][nf], 0, 0, 0);
  }

  // ---- epilogue: bias + stats; C through LDS (reuse Bs) for full-line stores ----
  float breg[4];
  #pragma unroll
  for (int nf = 0; nf < 4; ++nf) breg[nf] = bias[n0 + nf * 16 + fc];

  __syncthreads();   // all waves done reading Bs
  u16* Cl = (u16*)Bs;  // [128][64]
  float cs_[4] = {}, cq_[4] = {};
  #pragma unroll
  for (int mf = 0; mf < 2; ++mf) {
    #pragma unroll
    for (int j = 0; j < 4; ++j) {
      int rl = w * 32 + mf * 16 + c16 * 4 + j;
      bool valid = (m0 + rl) < M;
      #pragma unroll
      for (int nf = 0; nf < 4; ++nf) {
        float v = acc[mf][nf][j] + breg[nf];
        Cl[rl * 64 + nf * 16 + fc] = f2bf(v);
        if (DO_STATS && valid) { cs_[nf] += v; cq_[nf] = fmaf(v, v, cq_[nf]); }
      }
    }
  }
  __syncthreads();
  #pragma unroll
  for (int j2 = 0; j2 < 4; ++j2) {
    int ci = j2 * 256 + t;               // 0..1023 chunks
    int row = ci >> 3;
    int cx = ci & 7;
    int rg = m0 + row;
    if (rg < M)
      *(uint4*)(C + (size_t)rg * 128 + n0 + cx * 8) = *(const uint4*)&Cl[row * 64 + cx * 8];
  }

  if (DO_STATS) {
    #pragma unroll
    for (int nf = 0; nf < 4; ++nf) {
      float s = cs_[nf], q = cq_[nf];
      s += __shfl_xor(s, 16, 64); s += __shfl_xor(s, 32, 64);
      q += __shfl_xor(q, 16, 64); q += __shfl_xor(q, 32, 64);
      if (c16 == 0) {
        atomicAdd(&bnbuf[nf * 16 + fc], s);
        atomicAdd(&bnbuf[64 + nf * 16 + fc], q);
      }
    }
    __syncthreads();
    if (t < 128) {
      int idx = (t < 64) ? (n0 + t) : (128 + n0 + (t - 64));
      atomicAdd(&ssum_out[idx], bnbuf[t]);
    }
  }
}

// ================= fused encoder: x-MLP -> LDS A-tile -> GEMM. BM=64, grid (782,2) =================
__global__ __launch_bounds__(256) void k_enc(
    const float* __restrict__ x, const float* __restrict__ W1,
    const float* __restrict__ b1, const u16* __restrict__ Bp,
    const float* __restrict__ bias, u16* __restrict__ C, int M) {
  __shared__ __align__(16) u16 As[8][2048];   // 8 panels x (64 rows x 32) = 32KB; reused as C-stage [64][64]
  __shared__ __align__(16) u16 Bs[8][2048];   // 32KB
  __shared__ float xs[448];
  int t = threadIdx.x;
  int lane = t & 63;
  int w = t >> 6;
  int m0 = blockIdx.x * 64;
  int n0c = blockIdx.y * 64;
  int fc = lane & 15;
  int c16 = lane >> 4;

  // B loads first (land during MLP compute)
  uint4 bst[8];
  #pragma unroll
  for (int j = 0; j < 8; ++j) {
    int s = j * 256 + t;
    int p = s >> 8;
    int sp = s & 255;
    int row = sp >> 2;
    int cc = (sp & 3) ^ ((row >> 1) & 3);
    bst[j] = *(const uint4*)(Bp + (size_t)(n0c + row) * 256 + p * 32 + cc * 8);
  }
  for (int i = t; i < 448; i += 256) {
    int gi = m0 * 7 + i;
    xs[i] = (gi < M * 7) ? x[gi] : 0.f;
  }
  float w1r[7];
  #pragma unroll
  for (int k = 0; k < 7; ++k) w1r[k] = W1[t * 7 + k];
  float b1r = b1[t];
  __syncthreads();

  // h[r][t] -> A-tile swizzled (64 rows)
  int p = t >> 5;
  int cq = (t & 31) >> 3;
  int e8 = t & 7;
  for (int r = 0; r < 64; ++r) {
    float acc = b1r;
    #pragma unroll
    for (int k = 0; k < 7; ++k) acc = fmaf(w1r[k], xs[r * 7 + k], acc);
    As[p][r * 32 + (cq ^ ((r >> 1) & 3)) * 8 + e8] = f2bf(fmaxf(acc, 0.f));
  }
  // write B to LDS
  #pragma unroll
  for (int j = 0; j < 8; ++j) {
    int s = j * 256 + t;
    *(uint4*)&((u16*)Bs)[s * 8] = bst[j];
  }
  __syncthreads();

  // 2x2 wave tiling: rows (w&1)*32, cols (w>>1)*32
  f32x4 acc[2][2] = {};
  #pragma unroll
  for (int kt = 0; kt < 8; ++kt) {
    bf16x8 afr[2], bfr[2];
    #pragma unroll
    for (int mf = 0; mf < 2; ++mf) {
      int row = (w & 1) * 32 + mf * 16 + fc;
      int cs = c16 ^ ((row >> 1) & 3);
      afr[mf] = *(const bf16x8*)&As[kt][row * 32 + cs * 8];
    }
    #pragma unroll
    for (int nf = 0; nf < 2; ++nf) {
      int row = (w >> 1) * 32 + nf * 16 + fc;
      int cs = c16 ^ ((row >> 1) & 3);
      bfr[nf] = *(const bf16x8*)&Bs[kt][row * 32 + cs * 8];
    }
    #pragma unroll
    for (int mf = 0; mf < 2; ++mf)
      #pragma unroll
      for (int nf = 0; nf < 2; ++nf)
        acc[mf][nf] = __builtin_amdgcn_mfma_f32_16x16x32_bf16(afr[mf], bfr[nf], acc[mf][nf], 0, 0, 0);
  }

  float breg[2];
  #pragma unroll
  for (int nf = 0; nf < 2; ++nf) breg[nf] = bias[n0c + (w >> 1) * 32 + nf * 16 + fc];
  __syncthreads();   // done reading As
  u16* Cl = (u16*)As;  // [64][64]
  #pragma unroll
  for (int mf = 0; mf < 2; ++mf)
    #pragma unroll
    for (int j = 0; j < 4; ++j) {
      int rl = (w & 1) * 32 + mf * 16 + c16 * 4 + j;
      #pragma unroll
      for (int nf = 0; nf < 2; ++nf)
        Cl[rl * 64 + (w >> 1) * 32 + nf * 16 + fc] = f2bf(acc[mf][nf][j] + breg[nf]);
    }
  __syncthreads();
  #pragma unroll
  for (int j2 = 0; j2 < 2; ++j2) {
    int ci = j2 * 256 + t;                // 0..511 chunks
    int row = ci >> 3;
    int cx = ci & 7;
    int rg = m0 + row;
    if (rg < M)
      *(uint4*)(C + (size_t)rg * 128 + n0c + cx * 8) = *(const uint4*)&Cl[row * 64 + cx * 8];
  }
}

// ================= decoder: BM=64, full N=256 per block, grid 782, direct store =================
__global__ __launch_bounds__(256) void k_dec(
    const u16* __restrict__ z5, const u16* __restrict__ Bpd,
    const float* __restrict__ b1, const float* __restrict__ W2,
    const float* __restrict__ b2, float* __restrict__ out, int M) {
  __shared__ __align__(16) u16 Bs[4][8192];   // 4 panels x (256 rows x 32) = 64KB
  int t = threadIdx.x;
  int lane = t & 63;
  int w = t >> 6;
  int m0 = blockIdx.x * 64;
  int fc = lane & 15;
  int c16 = lane >> 4;

  // A fragments to registers: wave w owns rows w*16..+15
  bf16x8 af[4];
  {
    int rg = m0 + w * 16 + fc;
    rg = rg < M ? rg : M - 1;
    const u16* ar = z5 + (size_t)rg * 128 + c16 * 8;
    #pragma unroll
    for (int kt = 0; kt < 4; ++kt) af[kt] = *(const bf16x8*)(ar + kt * 32);
  }

  // B: 4096 slots in 2 reg-staged rounds
  #pragma unroll
  for (int r = 0; r < 2; ++r) {
    uint4 bst[8];
    #pragma unroll
    for (int j = 0; j < 8; ++j) {
      int s = r * 2048 + j * 256 + t;
      int p = s >> 10;
      int sp = s & 1023;
      int row = sp >> 2;
      int cc = (sp & 3) ^ ((row >> 1) & 3);
      bst[j] = *(const uint4*)(Bpd + (size_t)row * 128 + p * 32 + cc * 8);
    }
    #pragma unroll
    for (int j = 0; j < 8; ++j) {
      int s = r * 2048 + j * 256 + t;
      *(uint4*)&((u16*)Bs)[s * 8] = bst[j];
    }
  }
  __syncthreads();

  // K-loop: 16 col-fragments covering all 256 hidden cols
  f32x4 acc[16];
  #pragma unroll
  for (int nf = 0; nf < 16; ++nf) acc[nf] = (f32x4){0.f, 0.f, 0.f, 0.f};
  #pragma unroll
  for (int kt = 0; kt < 4; ++kt) {
    #pragma unroll
    for (int nf = 0; nf < 16; ++nf) {
      int row = nf * 16 + fc;
      int cs = c16 ^ ((row >> 1) & 3);
      bf16x8 bfr = *(const bf16x8*)&Bs[kt][row * 32 + cs * 8];
      acc[nf] = __builtin_amdgcn_mfma_f32_16x16x32_bf16(af[kt], bfr, acc[nf], 0, 0, 0);
    }
  }

  // epilogue: relu + W2 fold (lazy per-nf loads), shfl-reduce over 16 lanes, direct store
  float po[4][4] = {};
  #pragma unroll
  for (int nf = 0; nf < 16; ++nf) {
    int col = nf * 16 + fc;
    float b1v = b1[col];
    float w2v[4];
    #pragma unroll
    for (int o = 0; o < 4; ++o) w2v[o] = W2[o * 256 + col];
    #pragma unroll
    for (int j = 0; j < 4; ++j) {
      float hv = fmaxf(acc[nf][j] + b1v, 0.f);
      #pragma unroll
      for (int o = 0; o < 4; ++o) po[j][o] = fmaf(hv, w2v[o], po[j][o]);
    }
  }
  #pragma unroll
  for (int j = 0; j < 4; ++j)
    #pragma unroll
    for (int o = 0; o < 4; ++o) {
      float v = po[j][o];
      v += __shfl_xor(v, 1, 16);
      v += __shfl_xor(v, 2, 16);
      v += __shfl_xor(v, 4, 16);
      po[j][o] = v + __shfl_xor(v, 8, 16);
    }
  if (fc == 0) {
    #pragma unroll
    for (int j = 0; j < 4; ++j) {
      int rg = m0 + w * 16 + c16 * 4 + j;
      if (rg < M) {
        #pragma unroll
        for (int o = 0; o < 4; ++o) out[(size_t)rg * 4 + o] = po[j][o] + b2[o];
      }
    }
  }
}

// ---------------- launch ----------------
extern "C" void kernel_launch(void* const* d_in, const int* in_sizes, int n_in,
                              void* d_out, int out_size, void* d_ws, size_t ws_size,
                              hipStream_t stream) {
  const float* x     = (const float*)d_in[0];
  const int*   ei    = (const int*)d_in[1];
  const float* encW1 = (const float*)d_in[2];
  const float* encb1 = (const float*)d_in[3];
  const float* encW2 = (const float*)d_in[4];
  const float* encb2 = (const float*)d_in[5];
  const float* Wl    = (const float*)d_in[6];
  const float* bl    = (const float*)d_in[7];
  const float* Wr    = (const float*)d_in[8];
  const float* gamma = (const float*)d_in[9];
  const float* beta  = (const float*)d_in[10];
  const float* decW1 = (const float*)d_in[11];
  const float* decb1 = (const float*)d_in[12];
  const float* decW2 = (const float*)d_in[13];
  const float* decb2 = (const float*)d_in[14];
  float* out = (float*)d_out;

  const int M = M_NODES, E = E_EDGES;
  char* p = (char*)d_ws;
  auto take = [&](size_t b) { char* r = p; p += (b + 255) & ~(size_t)255; return r; };
  u16* zA     = (u16*)take((size_t)M * 128 * 2);
  u16* zB     = (u16*)take((size_t)M * 128 * 2);
  u16* zP     = (u16*)take((size_t)M * 128 * 2);
  u16* mean   = (u16*)take((size_t)M * 128 * 2);
  u16* Bpack  = (u16*)take((size_t)229376 * 2);
  int* cnt    = (int*)take((size_t)M * 4);
  int* bucket = (int*)take((size_t)M * BKT * 4);
  float* ssums = (float*)take(4 * 256 * 4);

  const int* srcp = ei;
  const int* dstp = ei + E;

  k_prep<<<896, 256, 0, stream>>>(encW2, Wl, Wr, decW1, Bpack);
  hipMemsetAsync(cnt, 0, (size_t)M * 4, stream);
  hipMemsetAsync(ssums, 0, 4 * 256 * 4, stream);
  k_place<<<(E + 255) / 256, 256, 0, stream>>>(srcp, dstp, cnt, bucket, E);

  const int GX64 = (M + 63) / 64;    // 782
  const int GX128 = (M + 127) / 128; // 391

  k_enc<<<dim3(GX64, 2), 256, 0, stream>>>(x, encW1, encb1, Bpack, encb2, zA, M);

  u16* cur = zA;
  u16* nxt = zB;
  for (int i = 0; i < 5; ++i) {
    if (i == 0) {
      k_agg<0><<<M / 4, 256, 0, stream>>>(cur, cnt, bucket, nullptr, nullptr, nullptr,
                                          mean, zP, M);
    } else {
      k_agg<1><<<M / 4, 256, 0, stream>>>(cur, cnt, bucket, ssums + (i - 1) * 256,
                                          gamma + (size_t)(i - 1) * 128,
                                          beta + (size_t)(i - 1) * 128, mean, zP, M);
    }
    const u16* A2 = (i == 0) ? cur : zP;
    if (i < 4) {
      k_gemm_reg<1><<<GX128 * 2, 256, 0, stream>>>(mean, A2, Bpack + 32768 + i * 32768,
                                                   bl + (size_t)i * 128, nxt, M,
                                                   ssums + i * 256);
    } else {
      k_gemm_reg<0><<<GX128 * 2, 256, 0, stream>>>(mean, A2, Bpack + 32768 + i * 32768,
                                                   bl + (size_t)i * 128, nxt, M, nullptr);
    }
    u16* tswap = cur; cur = nxt; nxt = tswap;
  }

  k_dec<<<GX64, 256, 0, stream>>>(cur, Bpack + 196608, decb1, decW2, decb2, out, M);
}

// Round 13
// 367.499 us; speedup vs baseline: 1.8133x; 1.0131x over previous
//
#include <hip/hip_runtime.h>

using u16 = unsigned short;
using u32 = unsigned int;

#define M_NODES 50000
#define E_EDGES 600000
#define EPS_BN 1e-5f
#define BKT 48

typedef __attribute__((ext_vector_type(8))) short bf16x8;
typedef __attribute__((ext_vector_type(4))) float f32x4;

__device__ __forceinline__ float bf2f(u16 v) {
  union { u32 u; float f; } x; x.u = ((u32)v) << 16; return x.f;
}
__device__ __forceinline__ float lo16f(u32 v) {
  union { u32 u; float f; } x; x.u = v << 16; return x.f;
}
__device__ __forceinline__ float hi16f(u32 v) {
  union { u32 u; float f; } x; x.u = v & 0xffff0000u; return x.f;
}
__device__ __forceinline__ u16 f2bf(float f) {
  union { float f; u32 u; } x; x.f = f;
  u32 r = x.u + 0x7fffu + ((x.u >> 16) & 1u);
  return (u16)(r >> 16);
}

// ---------------- bucket build ----------------
__global__ void k_place(const int* __restrict__ src, const int* __restrict__ dst,
                        int* __restrict__ cnt, int* __restrict__ bucket, int n) {
  int e = blockIdx.x * blockDim.x + threadIdx.x;
  if (e < n) {
    int d = dst[e];
    int p = atomicAdd(&cnt[d], 1);
    if (p < BKT) bucket[d * BKT + p] = src[e];
  }
}

// ---------------- weight prep ----------------
// [0,32768) encW2 [128][256]; [32768+i*32768) conv i [128][256]=[Wl|Wr]; [196608,229376) decW1 [256][128]
__global__ __launch_bounds__(256) void k_prep(const float* __restrict__ encW2,
                                              const float* __restrict__ Wl,
                                              const float* __restrict__ Wr,
                                              const float* __restrict__ decW1,
                                              u16* __restrict__ Bp) {
  int e = blockIdx.x * 256 + threadIdx.x;
  float v;
  if (e < 32768) {
    v = encW2[e];
  } else if (e < 196608) {
    int r = e - 32768;
    int i = r >> 15;
    int rr = r & 32767;
    int n = rr >> 8;
    int k = rr & 255;
    v = (k < 128) ? Wl[i * 16384 + n * 128 + k] : Wr[i * 16384 + n * 128 + (k - 128)];
  } else {
    v = decW1[e - 196608];
  }
  Bp[e] = f2bf(v);
}

// ---------------- fused mean-aggregation (+BN+relu of previous layer) ----------------
// XCD-aligned mapping: node-stripe (128 nodes) st satisfies st ≡ blockIdx.x (mod 8).
template <int TRANS>
__global__ __launch_bounds__(256) void k_agg(const u16* __restrict__ z,
                                             const int* __restrict__ cnt,
                                             const int* __restrict__ bucket,
                                             const float* __restrict__ ssum,
                                             const float* __restrict__ gamma,
                                             const float* __restrict__ beta,
                                             u16* __restrict__ mean,
                                             u16* __restrict__ zp, int M) {
  __shared__ float s_sc[256];
  int t = threadIdx.x;
  if (TRANS) {
    if (t < 128) {
      float m = ssum[t] * (1.0f / M_NODES);
      float var = ssum[128 + t] * (1.0f / M_NODES) - m * m;
      float s = gamma[t] * rsqrtf(var + EPS_BN);
      s_sc[t] = s;
      s_sc[128 + t] = beta[t] - m * s;
    }
    __syncthreads();
  }
  int lane = t & 63;
  int slot = lane >> 4;
  int fc = lane & 15;
  float sreg[8], treg[8];
  if (TRANS) {
    #pragma unroll
    for (int i = 0; i < 8; ++i) { sreg[i] = s_sc[fc * 8 + i]; treg[i] = s_sc[128 + fc * 8 + i]; }
  }
  // XCD-aligned block -> node-block mapping
  int rx = blockIdx.x & 7;
  int kx = blockIdx.x >> 3;               // [0,1568)
  int strip = rx + 8 * (kx >> 5);         // 128-node stripe, ≡ rx mod 8
  int nb = strip * 32 + (kx & 31);        // 4-node block
  int node = nb * 4 + (t >> 6);
  if (node >= M) return;                  // uniform per wave; no barriers after

  int deg = cnt[node];
  int nd = deg < BKT ? deg : BKT;
  const int* bk = bucket + (size_t)node * BKT;
  float a[8] = {};
  for (int j = slot; j < nd; j += 4) {
    int s = bk[j];
    uint4 v = *(const uint4*)(z + (size_t)s * 128 + fc * 8);
    float f[8] = {lo16f(v.x), hi16f(v.x), lo16f(v.y), hi16f(v.y),
                  lo16f(v.z), hi16f(v.z), lo16f(v.w), hi16f(v.w)};
    #pragma unroll
    for (int i = 0; i < 8; ++i) {
      float vv = TRANS ? fmaxf(fmaf(f[i], sreg[i], treg[i]), 0.f) : f[i];
      a[i] += vv;
    }
  }
  #pragma unroll
  for (int i = 0; i < 8; ++i) {
    a[i] += __shfl_xor(a[i], 16, 64);
    a[i] += __shfl_xor(a[i], 32, 64);
  }
  if (slot == 0) {
    float inv = 1.0f / (float)(deg > 1 ? deg : 1);
    uint4 r;
    r.x = (u32)f2bf(a[0] * inv) | ((u32)f2bf(a[1] * inv) << 16);
    r.y = (u32)f2bf(a[2] * inv) | ((u32)f2bf(a[3] * inv) << 16);
    r.z = (u32)f2bf(a[4] * inv) | ((u32)f2bf(a[5] * inv) << 16);
    r.w = (u32)f2bf(a[6] * inv) | ((u32)f2bf(a[7] * inv) << 16);
    *(uint4*)(mean + (size_t)node * 128 + fc * 8) = r;
  }
  if (TRANS && slot == 1) {
    uint4 v = *(const uint4*)(z + (size_t)node * 128 + fc * 8);
    float f[8] = {lo16f(v.x), hi16f(v.x), lo16f(v.y), hi16f(v.y),
                  lo16f(v.z), hi16f(v.z), lo16f(v.w), hi16f(v.w)};
    u16 o[8];
    #pragma unroll
    for (int i = 0; i < 8; ++i) o[i] = f2bf(fmaxf(fmaf(f[i], sreg[i], treg[i]), 0.f));
    uint4 r;
    r.x = (u32)o[0] | ((u32)o[1] << 16);
    r.y = (u32)o[2] | ((u32)o[3] << 16);
    r.z = (u32)o[4] | ((u32)o[5] << 16);
    r.w = (u32)o[6] | ((u32)o[7] << 16);
    *(uint4*)(zp + (size_t)node * 128 + fc * 8) = r;
  }
}

// ================= conv GEMM: A in regs, B reg->LDS, C restaged in LDS =================
// XCD-aligned: stripe s ≡ blockIdx.x (mod 8). launch 784 blocks.
template <int DO_STATS>
__global__ __launch_bounds__(256) void k_gemm_reg(
    const u16* __restrict__ A1, const u16* __restrict__ A2,
    const u16* __restrict__ Bp, const float* __restrict__ bias,
    u16* __restrict__ C, int M, float* __restrict__ ssum_out) {
  __shared__ __align__(16) u16 Bs[8][2048];   // 32KB; reused as C-stage [128][64]
  __shared__ float bnbuf[128];
  int t = threadIdx.x;
  int lane = t & 63;
  int w = t >> 6;
  int rx = blockIdx.x & 7;
  int hx = (blockIdx.x >> 3) & 1;
  int qx = blockIdx.x >> 4;               // [0,49)
  int s128 = qx * 8 + rx;                 // stripe, ≡ rx mod 8
  int m0 = s128 * 128;
  if (m0 >= M) return;
  int n0 = hx * 64;
  int fc = lane & 15;
  int c16 = lane >> 4;

  if (DO_STATS && t < 128) bnbuf[t] = 0.f;

  // ---- B: plain uint4 loads to regs (all independent, issued first) ----
  uint4 bst[8];
  #pragma unroll
  for (int j = 0; j < 8; ++j) {
    int s = j * 256 + t;                  // 0..2047 16B slots
    int p = s >> 8;
    int sp = s & 255;
    int row = sp >> 2;
    int cc = (sp & 3) ^ ((row >> 1) & 3);
    bst[j] = *(const uint4*)(Bp + (size_t)(n0 + row) * 256 + p * 32 + cc * 8);
  }

  // ---- A fragments straight to registers: 16 independent dwordx4 per lane ----
  bf16x8 af[8][2];
  int wrb = m0 + w * 32;
  #pragma unroll
  for (int mf = 0; mf < 2; ++mf) {
    int rg = wrb + mf * 16 + fc;
    rg = rg < M ? rg : M - 1;
    const u16* a1r = A1 + (size_t)rg * 128 + c16 * 8;
    const u16* a2r = A2 + (size_t)rg * 128 + c16 * 8;
    #pragma unroll
    for (int kt = 0; kt < 4; ++kt) af[kt][mf] = *(const bf16x8*)(a1r + kt * 32);
    #pragma unroll
    for (int kt = 0; kt < 4; ++kt) af[4 + kt][mf] = *(const bf16x8*)(a2r + kt * 32);
  }

  // ---- write B to LDS ----
  #pragma unroll
  for (int j = 0; j < 8; ++j) {
    int s = j * 256 + t;
    *(uint4*)&((u16*)Bs)[s * 8] = bst[j];
  }
  __syncthreads();

  // ---- barrier-free K-loop ----
  f32x4 acc[2][4] = {};
  #pragma unroll
  for (int kt = 0; kt < 8; ++kt) {
    bf16x8 bfr[4];
    #pragma unroll
    for (int nf = 0; nf < 4; ++nf) {
      int row = nf * 16 + fc;
      int cs = c16 ^ ((row >> 1) & 3);
      bfr[nf] = *(const bf16x8*)&Bs[kt][row * 32 + cs * 8];
    }
    #pragma unroll
    for (int mf = 0; mf < 2; ++mf)
      #pragma unroll
      for (int nf = 0; nf < 4; ++nf)
        acc[mf][nf] = __builtin_amdgcn_mfma_f32_16x16x32_bf16(af[kt][mf], bfr[nf], acc[mf][nf], 0, 0, 0);
  }

  // ---- epilogue: bias + stats; C through LDS (reuse Bs) for full-line stores ----
  float breg[4];
  #pragma unroll
  for (int nf = 0; nf < 4; ++nf) breg[nf] = bias[n0 + nf * 16 + fc];

  __syncthreads();   // all waves done reading Bs
  u16* Cl = (u16*)Bs;  // [128][64]
  float cs_[4] = {}, cq_[4] = {};
  #pragma unroll
  for (int mf = 0; mf < 2; ++mf) {
    #pragma unroll
    for (int j = 0; j < 4; ++j) {
      int rl = w * 32 + mf * 16 + c16 * 4 + j;
      bool valid = (m0 + rl) < M;
      #pragma unroll
      for (int nf = 0; nf < 4; ++nf) {
        float v = acc[mf][nf][j] + breg[nf];
        Cl[rl * 64 + nf * 16 + fc] = f2bf(v);
        if (DO_STATS && valid) { cs_[nf] += v; cq_[nf] = fmaf(v, v, cq_[nf]); }
      }
    }
  }
  __syncthreads();
  #pragma unroll
  for (int j2 = 0; j2 < 4; ++j2) {
    int ci = j2 * 256 + t;               // 0..1023 chunks
    int row = ci >> 3;
    int cx = ci & 7;
    int rg = m0 + row;
    if (rg < M)
      *(uint4*)(C + (size_t)rg * 128 + n0 + cx * 8) = *(const uint4*)&Cl[row * 64 + cx * 8];
  }

  if (DO_STATS) {
    #pragma unroll
    for (int nf = 0; nf < 4; ++nf) {
      float s = cs_[nf], q = cq_[nf];
      s += __shfl_xor(s, 16, 64); s += __shfl_xor(s, 32, 64);
      q += __shfl_xor(q, 16, 64); q += __shfl_xor(q, 32, 64);
      if (c16 == 0) {
        atomicAdd(&bnbuf[nf * 16 + fc], s);
        atomicAdd(&bnbuf[64 + nf * 16 + fc], q);
      }
    }
    __syncthreads();
    if (t < 128) {
      int idx = (t < 64) ? (n0 + t) : (128 + n0 + (t - 64));
      atomicAdd(&ssum_out[idx], bnbuf[t]);
    }
  }
}

// ================= fused encoder: x-MLP -> LDS A-tile -> GEMM. BM=64, 1D grid 1568 =================
// XCD-aligned: 128-row super-stripe s ≡ blockIdx.x (mod 8).
__global__ __launch_bounds__(256) void k_enc(
    const float* __restrict__ x, const float* __restrict__ W1,
    const float* __restrict__ b1, const u16* __restrict__ Bp,
    const float* __restrict__ bias, u16* __restrict__ C, int M) {
  __shared__ __align__(16) u16 As[8][2048];   // 32KB; reused as C-stage [64][64]
  __shared__ __align__(16) u16 Bs[8][2048];   // 32KB
  __shared__ float xs[448];
  int t = threadIdx.x;
  int lane = t & 63;
  int w = t >> 6;
  int rx = blockIdx.x & 7;
  int kx = (blockIdx.x >> 3) & 3;
  int qx = blockIdx.x >> 5;               // [0,49)
  int s128 = qx * 8 + rx;
  int e64 = s128 * 2 + (kx & 1);          // 64-row stripe
  int m0 = e64 * 64;
  if (m0 >= M) return;
  int n0c = (kx >> 1) * 64;
  int fc = lane & 15;
  int c16 = lane >> 4;

  // B loads first (land during MLP compute)
  uint4 bst[8];
  #pragma unroll
  for (int j = 0; j < 8; ++j) {
    int s = j * 256 + t;
    int p = s >> 8;
    int sp = s & 255;
    int row = sp >> 2;
    int cc = (sp & 3) ^ ((row >> 1) & 3);
    bst[j] = *(const uint4*)(Bp + (size_t)(n0c + row) * 256 + p * 32 + cc * 8);
  }
  for (int i = t; i < 448; i += 256) {
    int gi = m0 * 7 + i;
    xs[i] = (gi < M * 7) ? x[gi] : 0.f;
  }
  float w1r[7];
  #pragma unroll
  for (int k = 0; k < 7; ++k) w1r[k] = W1[t * 7 + k];
  float b1r = b1[t];
  __syncthreads();

  // h[r][t] -> A-tile swizzled (64 rows)
  int p = t >> 5;
  int cq = (t & 31) >> 3;
  int e8 = t & 7;
  for (int r = 0; r < 64; ++r) {
    float acc = b1r;
    #pragma unroll
    for (int k = 0; k < 7; ++k) acc = fmaf(w1r[k], xs[r * 7 + k], acc);
    As[p][r * 32 + (cq ^ ((r >> 1) & 3)) * 8 + e8] = f2bf(fmaxf(acc, 0.f));
  }
  // write B to LDS
  #pragma unroll
  for (int j = 0; j < 8; ++j) {
    int s = j * 256 + t;
    *(uint4*)&((u16*)Bs)[s * 8] = bst[j];
  }
  __syncthreads();

  // 2x2 wave tiling: rows (w&1)*32, cols (w>>1)*32
  f32x4 acc[2][2] = {};
  #pragma unroll
  for (int kt = 0; kt < 8; ++kt) {
    bf16x8 afr[2], bfr[2];
    #pragma unroll
    for (int mf = 0; mf < 2; ++mf) {
      int row = (w & 1) * 32 + mf * 16 + fc;
      int cs = c16 ^ ((row >> 1) & 3);
      afr[mf] = *(const bf16x8*)&As[kt][row * 32 + cs * 8];
    }
    #pragma unroll
    for (int nf = 0; nf < 2; ++nf) {
      int row = (w >> 1) * 32 + nf * 16 + fc;
      int cs = c16 ^ ((row >> 1) & 3);
      bfr[nf] = *(const bf16x8*)&Bs[kt][row * 32 + cs * 8];
    }
    #pragma unroll
    for (int mf = 0; mf < 2; ++mf)
      #pragma unroll
      for (int nf = 0; nf < 2; ++nf)
        acc[mf][nf] = __builtin_amdgcn_mfma_f32_16x16x32_bf16(afr[mf], bfr[nf], acc[mf][nf], 0, 0, 0);
  }

  float breg[2];
  #pragma unroll
  for (int nf = 0; nf < 2; ++nf) breg[nf] = bias[n0c + (w >> 1) * 32 + nf * 16 + fc];
  __syncthreads();   // done reading As
  u16* Cl = (u16*)As;  // [64][64]
  #pragma unroll
  for (int mf = 0; mf < 2; ++mf)
    #pragma unroll
    for (int j = 0; j < 4; ++j) {
      int rl = (w & 1) * 32 + mf * 16 + c16 * 4 + j;
      #pragma unroll
      for (int nf = 0; nf < 2; ++nf)
        Cl[rl * 64 + (w >> 1) * 32 + nf * 16 + fc] = f2bf(acc[mf][nf][j] + breg[nf]);
    }
  __syncthreads();
  #pragma unroll
  for (int j2 = 0; j2 < 2; ++j2) {
    int ci = j2 * 256 + t;                // 0..511 chunks
    int row = ci >> 3;
    int cx = ci & 7;
    int rg = m0 + row;
    if (rg < M)
      *(uint4*)(C + (size_t)rg * 128 + n0c + cx * 8) = *(const uint4*)&Cl[row * 64 + cx * 8];
  }
}

// ================= decoder: BM=64, full N=256 per block, 1D grid 784, direct store =================
// XCD-aligned: 128-row super-stripe s ≡ blockIdx.x (mod 8).
__global__ __launch_bounds__(256) void k_dec(
    const u16* __restrict__ z5, const u16* __restrict__ Bpd,
    const float* __restrict__ b1, const float* __restrict__ W2,
    const float* __restrict__ b2, float* __restrict__ out, int M) {
  __shared__ __align__(16) u16 Bs[4][8192];   // 64KB
  int t = threadIdx.x;
  int lane = t & 63;
  int w = t >> 6;
  int rx = blockIdx.x & 7;
  int kx = (blockIdx.x >> 3) & 1;
  int qx = blockIdx.x >> 4;               // [0,49)
  int s128 = qx * 8 + rx;
  int e64 = s128 * 2 + kx;
  int m0 = e64 * 64;
  if (m0 >= M) return;
  int fc = lane & 15;
  int c16 = lane >> 4;

  // A fragments to registers: wave w owns rows w*16..+15
  bf16x8 af[4];
  {
    int rg = m0 + w * 16 + fc;
    rg = rg < M ? rg : M - 1;
    const u16* ar = z5 + (size_t)rg * 128 + c16 * 8;
    #pragma unroll
    for (int kt = 0; kt < 4; ++kt) af[kt] = *(const bf16x8*)(ar + kt * 32);
  }

  // B: 4096 slots in 2 reg-staged rounds
  #pragma unroll
  for (int r = 0; r < 2; ++r) {
    uint4 bst[8];
    #pragma unroll
    for (int j = 0; j < 8; ++j) {
      int s = r * 2048 + j * 256 + t;
      int p = s >> 10;
      int sp = s & 1023;
      int row = sp >> 2;
      int cc = (sp & 3) ^ ((row >> 1) & 3);
      bst[j] = *(const uint4*)(Bpd + (size_t)row * 128 + p * 32 + cc * 8);
    }
    #pragma unroll
    for (int j = 0; j < 8; ++j) {
      int s = r * 2048 + j * 256 + t;
      *(uint4*)&((u16*)Bs)[s * 8] = bst[j];
    }
  }
  __syncthreads();

  // K-loop: 16 col-fragments covering all 256 hidden cols
  f32x4 acc[16];
  #pragma unroll
  for (int nf = 0; nf < 16; ++nf) acc[nf] = (f32x4){0.f, 0.f, 0.f, 0.f};
  #pragma unroll
  for (int kt = 0; kt < 4; ++kt) {
    #pragma unroll
    for (int nf = 0; nf < 16; ++nf) {
      int row = nf * 16 + fc;
      int cs = c16 ^ ((row >> 1) & 3);
      bf16x8 bfr = *(const bf16x8*)&Bs[kt][row * 32 + cs * 8];
      acc[nf] = __builtin_amdgcn_mfma_f32_16x16x32_bf16(af[kt], bfr, acc[nf], 0, 0, 0);
    }
  }

  // epilogue: relu + W2 fold, shfl-reduce over 16 lanes, direct store
  float po[4][4] = {};
  #pragma unroll
  for (int nf = 0; nf < 16; ++nf) {
    int col = nf * 16 + fc;
    float b1v = b1[col];
    float w2v[4];
    #pragma unroll
    for (int o = 0; o < 4; ++o) w2v[o] = W2[o * 256 + col];
    #pragma unroll
    for (int j = 0; j < 4; ++j) {
      float hv = fmaxf(acc[nf][j] + b1v, 0.f);
      #pragma unroll
      for (int o = 0; o < 4; ++o) po[j][o] = fmaf(hv, w2v[o], po[j][o]);
    }
  }
  #pragma unroll
  for (int j = 0; j < 4; ++j)
    #pragma unroll
    for (int o = 0; o < 4; ++o) {
      float v = po[j][o];
      v += __shfl_xor(v, 1, 16);
      v += __shfl_xor(v, 2, 16);
      v += __shfl_xor(v, 4, 16);
      po[j][o] = v + __shfl_xor(v, 8, 16);
    }
  if (fc == 0) {
    #pragma unroll
    for (int j = 0; j < 4; ++j) {
      int rg = m0 + w * 16 + c16 * 4 + j;
      if (rg < M) {
        #pragma unroll
        for (int o = 0; o < 4; ++o) out[(size_t)rg * 4 + o] = po[j][o] + b2[o];
      }
    }
  }
}

// ---------------- launch ----------------
extern "C" void kernel_launch(void* const* d_in, const int* in_sizes, int n_in,
                              void* d_out, int out_size, void* d_ws, size_t ws_size,
                              hipStream_t stream) {
  const float* x     = (const float*)d_in[0];
  const int*   ei    = (const int*)d_in[1];
  const float* encW1 = (const float*)d_in[2];
  const float* encb1 = (const float*)d_in[3];
  const float* encW2 = (const float*)d_in[4];
  const float* encb2 = (const float*)d_in[5];
  const float* Wl    = (const float*)d_in[6];
  const float* bl    = (const float*)d_in[7];
  const float* Wr    = (const float*)d_in[8];
  const float* gamma = (const float*)d_in[9];
  const float* beta  = (const float*)d_in[10];
  const float* decW1 = (const float*)d_in[11];
  const float* decb1 = (const float*)d_in[12];
  const float* decW2 = (const float*)d_in[13];
  const float* decb2 = (const float*)d_in[14];
  float* out = (float*)d_out;

  const int M = M_NODES, E = E_EDGES;
  char* p = (char*)d_ws;
  auto take = [&](size_t b) { char* r = p; p += (b + 255) & ~(size_t)255; return r; };
  u16* zA     = (u16*)take((size_t)M * 128 * 2);
  u16* zB     = (u16*)take((size_t)M * 128 * 2);
  u16* zP     = (u16*)take((size_t)M * 128 * 2);
  u16* mean   = (u16*)take((size_t)M * 128 * 2);
  u16* Bpack  = (u16*)take((size_t)229376 * 2);
  int* cnt    = (int*)take((size_t)M * 4);
  int* bucket = (int*)take((size_t)M * BKT * 4);
  float* ssums = (float*)take(4 * 256 * 4);

  const int* srcp = ei;
  const int* dstp = ei + E;

  k_prep<<<896, 256, 0, stream>>>(encW2, Wl, Wr, decW1, Bpack);
  hipMemsetAsync(cnt, 0, (size_t)M * 4, stream);
  hipMemsetAsync(ssums, 0, 4 * 256 * 4, stream);
  k_place<<<(E + 255) / 256, 256, 0, stream>>>(srcp, dstp, cnt, bucket, E);

  k_enc<<<1568, 256, 0, stream>>>(x, encW1, encb1, Bpack, encb2, zA, M);

  u16* cur = zA;
  u16* nxt = zB;
  for (int i = 0; i < 5; ++i) {
    if (i == 0) {
      k_agg<0><<<12544, 256, 0, stream>>>(cur, cnt, bucket, nullptr, nullptr, nullptr,
                                          mean, zP, M);
    } else {
      k_agg<1><<<12544, 256, 0, stream>>>(cur, cnt, bucket, ssums + (i - 1) * 256,
                                          gamma + (size_t)(i - 1) * 128,
                                          beta + (size_t)(i - 1) * 128, mean, zP, M);
    }
    const u16* A2 = (i == 0) ? cur : zP;
    if (i < 4) {
      k_gemm_reg<1><<<784, 256, 0, stream>>>(mean, A2, Bpack + 32768 + i * 32768,
                                             bl + (size_t)i * 128, nxt, M,
                                             ssums + i * 256);
    } else {
      k_gemm_reg<0><<<784, 256, 0, stream>>>(mean, A2, Bpack + 32768 + i * 32768,
                                             bl + (size_t)i * 128, nxt, M, nullptr);
    }
    u16* tswap = cur; cur = nxt; nxt = tswap;
  }

  k_dec<<<784, 256, 0, stream>>>(cur, Bpack + 196608, decb1, decW2, decb2, out, M);
}